// Round 1
// baseline (1259.693 us; speedup 1.0000x reference)
//
#include <hip/hip_runtime.h>
#include <math.h>

#define N0 20000
#define N1 15000
#define N2 15000
#define NN 50000          // total nodes
#define EE 800000         // edges
#define NHEAD 4
#define DHEAD 64
#define SLOPE 0.2f
#define ALPHA 0.05f

// ---------------- CSR build ----------------

__global__ void hist_kernel(const int* __restrict__ dst, int* __restrict__ deg, int E_) {
    int e = blockIdx.x * blockDim.x + threadIdx.x;
    if (e < E_) atomicAdd(&deg[dst[e]], 1);
}

__global__ __launch_bounds__(1024) void scan_excl_kernel(const int* __restrict__ deg,
                                                         int* __restrict__ rowstart, int n) {
    __shared__ int sh[1024];
    __shared__ int carry_s;
    int tid = threadIdx.x;
    if (tid == 0) carry_s = 0;
    __syncthreads();
    for (int base = 0; base < n; base += 1024) {
        int i = base + tid;
        int v = (i < n) ? deg[i] : 0;
        sh[tid] = v;
        __syncthreads();
        for (int off = 1; off < 1024; off <<= 1) {
            int t = (tid >= off) ? sh[tid - off] : 0;
            __syncthreads();
            sh[tid] += t;
            __syncthreads();
        }
        int carry = carry_s;
        if (i < n) rowstart[i] = carry + sh[tid] - v;
        __syncthreads();
        if (tid == 0) carry_s += sh[1023];
        __syncthreads();
    }
    if (tid == 0) rowstart[n] = carry_s;
}

__global__ void scatter_kernel(const int* __restrict__ src, const int* __restrict__ dst,
                               int* __restrict__ cursor, int* __restrict__ ebuf,
                               int* __restrict__ csrc, int E_) {
    int e = blockIdx.x * blockDim.x + threadIdx.x;
    if (e >= E_) return;
    int p = atomicAdd(&cursor[dst[e]], 1);
    ebuf[p] = e;
    csrc[p] = src[e];
}

// ---------------- es table: es[t,h] = sum_j ae[h,j] * dot(We[h*64+j,:], etab[t,:]) ----------------
// grid = NET * H blocks, 64 threads each. block b -> t = b/H, h = b%H.

__global__ void es_table_kernel(const float* __restrict__ etab, const float* __restrict__ We,
                                const float* __restrict__ ae, float* __restrict__ es, int H) {
    int b = blockIdx.x;
    int t = b / H, h = b % H;
    int j = threadIdx.x;   // 0..63
    const float* w = We + (size_t)(h * 64 + j) * 64;
    const float* e = etab + t * 64;
    float s = 0.f;
    #pragma unroll
    for (int k = 0; k < 64; k += 4) {
        float4 wv = *(const float4*)(w + k);
        float4 ev = *(const float4*)(e + k);
        s += wv.x * ev.x + wv.y * ev.y + wv.z * ev.z + wv.w * ev.w;
    }
    s *= ae[h * 64 + j];
    #pragma unroll
    for (int off = 32; off > 0; off >>= 1) s += __shfl_down(s, off);
    if (j == 0) es[t * H + h] = s;
}

// ---------------- tiled fp32 GEMM: C[m,n] = sum_k A[m,k]*B[n,k] (+bias[n]) ----------------

template<int BM, int BN, int BK, int TM, int TN>
__global__ __launch_bounds__(256) void gemm_nt(const float* __restrict__ A, const float* __restrict__ B,
                                               const float* __restrict__ bias, float* __restrict__ C,
                                               int M, int N, int K) {
    constexpr int BMP = BM + 4, BNP = BN + 4;
    __shared__ float As[BK * BMP];
    __shared__ float Bs[BK * BNP];
    const int tid = threadIdx.x;
    const int m0 = blockIdx.x * BM;
    const int n0 = blockIdx.y * BN;
    const int tx = tid % (BN / TN);
    const int ty = tid / (BN / TN);
    float acc[TM][TN] = {};
    constexpr int LDA = (BM * BK) / (256 * 4);
    constexpr int LDB = (BN * BK) / (256 * 4);
    for (int k0 = 0; k0 < K; k0 += BK) {
        #pragma unroll
        for (int l = 0; l < LDA; l++) {
            int idx = (tid + l * 256) * 4;
            int row = idx / BK, col = idx % BK;
            int gr = m0 + row; if (gr >= M) gr = M - 1;
            float4 v = *(const float4*)(A + (size_t)gr * K + k0 + col);
            As[(col + 0) * BMP + row] = v.x;
            As[(col + 1) * BMP + row] = v.y;
            As[(col + 2) * BMP + row] = v.z;
            As[(col + 3) * BMP + row] = v.w;
        }
        #pragma unroll
        for (int l = 0; l < LDB; l++) {
            int idx = (tid + l * 256) * 4;
            int row = idx / BK, col = idx % BK;
            int gn = n0 + row;   // N % BN == 0 for all our launches
            float4 v = *(const float4*)(B + (size_t)gn * K + k0 + col);
            Bs[(col + 0) * BNP + row] = v.x;
            Bs[(col + 1) * BNP + row] = v.y;
            Bs[(col + 2) * BNP + row] = v.z;
            Bs[(col + 3) * BNP + row] = v.w;
        }
        __syncthreads();
        #pragma unroll
        for (int k = 0; k < BK; k++) {
            float a[TM], b[TN];
            #pragma unroll
            for (int i = 0; i < TM; i += 4) {
                float4 v = *(const float4*)(&As[k * BMP + ty * TM + i]);
                a[i] = v.x; a[i+1] = v.y; a[i+2] = v.z; a[i+3] = v.w;
            }
            #pragma unroll
            for (int j = 0; j < TN; j += 4) {
                float4 v = *(const float4*)(&Bs[k * BNP + tx * TN + j]);
                b[j] = v.x; b[j+1] = v.y; b[j+2] = v.z; b[j+3] = v.w;
            }
            #pragma unroll
            for (int i = 0; i < TM; i++)
                #pragma unroll
                for (int j = 0; j < TN; j++)
                    acc[i][j] = fmaf(a[i], b[j], acc[i][j]);
        }
        __syncthreads();
    }
    #pragma unroll
    for (int i = 0; i < TM; i++) {
        int m = m0 + ty * TM + i;
        if (m < M) {
            #pragma unroll
            for (int j = 0; j < TN; j += 4) {
                int n = n0 + tx * TN + j;
                float4 v;
                v.x = acc[i][j]; v.y = acc[i][j+1]; v.z = acc[i][j+2]; v.w = acc[i][j+3];
                if (bias) { v.x += bias[n]; v.y += bias[n+1]; v.z += bias[n+2]; v.w += bias[n+3]; }
                *(float4*)(C + (size_t)m * N + n) = v;
            }
        }
    }
}

// ---------------- layer-2 small-N GEMM: feat2[m,c]=dot(A[m,:],Wg[c,:]); res2 from Wr ----------------

__global__ __launch_bounds__(256) void gemm_feat2(const float* __restrict__ A,
                                                  const float* __restrict__ Wg, const float* __restrict__ Wr,
                                                  float* __restrict__ feat2, float* __restrict__ res2, int M) {
    __shared__ float As[8 * 256];
    int tid = threadIdx.x;
    int m0 = blockIdx.x * 8;
    #pragma unroll
    for (int l = 0; l < 2; l++) {
        int idx = (tid + l * 256) * 4;
        int rr = idx >> 8, cc = idx & 255;
        int gm = m0 + rr; if (gm >= M) gm = M - 1;
        *(float4*)(As + idx) = *(const float4*)(A + (size_t)gm * 256 + cc);
    }
    __syncthreads();
    int r = tid >> 5, c = tid & 31;
    const float* B = (c < 16) ? (Wg + c * 256) : (Wr + (c - 16) * 256);
    float s = 0.f;
    #pragma unroll 8
    for (int k = 0; k < 256; k += 4) {
        float4 av = *(const float4*)(As + r * 256 + k);
        float4 bv = *(const float4*)(B + k);
        s += av.x * bv.x + av.y * bv.y + av.z * bv.z + av.w * bv.w;
    }
    int m = m0 + r;
    if (m < M) {
        if (c < 16) feat2[m * 16 + c] = s;
        else        res2[m * 16 + (c - 16)] = s;
    }
}

// ---------------- per-node el/er ----------------

template<int H, int D>
__global__ void node_elr(const float* __restrict__ feat, const float* __restrict__ al,
                         const float* __restrict__ ar, float* __restrict__ el,
                         float* __restrict__ er, int nN) {
    int t = blockIdx.x * blockDim.x + threadIdx.x;
    if (t >= nN * H) return;
    int n = t / H, h = t % H;
    const float* f = feat + (size_t)n * (H * D) + h * D;
    const float* a = al + h * D;
    const float* r = ar + h * D;
    float sl = 0.f, sr = 0.f;
    #pragma unroll
    for (int j = 0; j < D; j += 4) {
        float4 fv = *(const float4*)(f + j);
        float4 av = *(const float4*)(a + j);
        float4 rv = *(const float4*)(r + j);
        sl += fv.x * av.x + fv.y * av.y + fv.z * av.z + fv.w * av.w;
        sr += fv.x * rv.x + fv.y * rv.y + fv.z * rv.z + fv.w * rv.w;
    }
    el[t] = sl; er[t] = sr;
}

// ---------------- edge logits ----------------

__global__ void edge_logits_h4(const int* __restrict__ src, const int* __restrict__ dst,
                               const int* __restrict__ et, const float* __restrict__ el,
                               const float* __restrict__ er, const float* __restrict__ es,
                               float* __restrict__ lg, int E_) {
    int e = blockIdx.x * blockDim.x + threadIdx.x;
    if (e >= E_) return;
    int s = src[e], d = dst[e], t = et[e];
    float4 a = *(const float4*)(el + s * 4);
    float4 b = *(const float4*)(er + d * 4);
    float4 c = *(const float4*)(es + t * 4);
    float4 r;
    float v;
    v = a.x + b.x + c.x; r.x = v > 0.f ? v : SLOPE * v;
    v = a.y + b.y + c.y; r.y = v > 0.f ? v : SLOPE * v;
    v = a.z + b.z + c.z; r.z = v > 0.f ? v : SLOPE * v;
    v = a.w + b.w + c.w; r.w = v > 0.f ? v : SLOPE * v;
    *(float4*)(lg + e * 4) = r;
}

__global__ void edge_logits_h1(const int* __restrict__ src, const int* __restrict__ dst,
                               const int* __restrict__ et, const float* __restrict__ el,
                               const float* __restrict__ er, const float* __restrict__ es,
                               float* __restrict__ lg, int E_) {
    int e = blockIdx.x * blockDim.x + threadIdx.x;
    if (e >= E_) return;
    float v = el[src[e]] + er[dst[e]] + es[et[e]];
    lg[e] = v > 0.f ? v : SLOPE * v;
}

// ---------------- edge softmax (per (dst,head) segment; m/s in registers) ----------------

template<int H>
__global__ void edge_softmax_k(const int* __restrict__ rowstart, const int* __restrict__ ebuf,
                               const float* __restrict__ lg, const float* __restrict__ a_prev,
                               float* __restrict__ a_out, int nN) {
    int t = blockIdx.x * blockDim.x + threadIdx.x;
    if (t >= nN * H) return;
    int n = t / H, h = t % H;
    int r0 = rowstart[n], r1 = rowstart[n + 1];
    float m = -INFINITY;
    for (int i = r0; i < r1; i++) {
        float v = lg[ebuf[i] * H + h];
        m = fmaxf(m, v);
    }
    float ssum = 0.f;
    for (int i = r0; i < r1; i++) {
        int idx = ebuf[i] * H + h;
        float v = expf(lg[idx] - m);
        a_out[idx] = v;           // a_out may alias lg; each idx owned by this thread
        ssum += v;
    }
    float inv = 1.f / (ssum + 1e-9f);
    for (int i = r0; i < r1; i++) {
        int idx = ebuf[i] * H + h;
        float a = a_out[idx] * inv;
        if (a_prev) a = a * (1.f - ALPHA) + ALPHA * a_prev[idx];
        a_out[idx] = a;
    }
}

// ---------------- aggregation: one wave per dst (H=4, D=64 -> 256 floats) ----------------

__global__ __launch_bounds__(256) void aggregate256(const int* __restrict__ rowstart,
                                                    const int* __restrict__ ebuf,
                                                    const int* __restrict__ csrc,
                                                    const float* __restrict__ a,
                                                    const float* __restrict__ feat,
                                                    float* __restrict__ out, int nN) {
    int n = blockIdx.x * 4 + (threadIdx.x >> 6);
    int lane = threadIdx.x & 63;
    if (n >= nN) return;
    int r0 = rowstart[n], r1 = rowstart[n + 1];
    int h = lane >> 4;
    float4 acc = {0.f, 0.f, 0.f, 0.f};
    for (int i = r0; i < r1; i++) {
        int e = ebuf[i];
        int s = csrc[i];
        float av = a[e * 4 + h];
        float4 f = *(const float4*)(feat + (size_t)s * 256 + lane * 4);
        acc.x += av * f.x; acc.y += av * f.y; acc.z += av * f.z; acc.w += av * f.w;
    }
    *(float4*)(out + (size_t)n * 256 + lane * 4) = acc;
}

// layer 2: H=1, 16 floats per dst -> 4 lanes per dst
__global__ __launch_bounds__(256) void aggregate16(const int* __restrict__ rowstart,
                                                   const int* __restrict__ ebuf,
                                                   const int* __restrict__ csrc,
                                                   const float* __restrict__ a,
                                                   const float* __restrict__ feat,
                                                   float* __restrict__ out, int nN) {
    int t = blockIdx.x * blockDim.x + threadIdx.x;
    int n = t >> 2, l = t & 3;
    if (n >= nN) return;
    int r0 = rowstart[n], r1 = rowstart[n + 1];
    float4 acc = {0.f, 0.f, 0.f, 0.f};
    for (int i = r0; i < r1; i++) {
        int e = ebuf[i];
        int s = csrc[i];
        float av = a[e];
        float4 f = *(const float4*)(feat + (size_t)s * 16 + l * 4);
        acc.x += av * f.x; acc.y += av * f.y; acc.z += av * f.z; acc.w += av * f.w;
    }
    *(float4*)(out + (size_t)n * 16 + l * 4) = acc;
}

// ---------------- elementwise ----------------

__global__ void elu_res_k(const float* __restrict__ in, const float* __restrict__ res,
                          float* __restrict__ out, int n4) {
    int t = blockIdx.x * blockDim.x + threadIdx.x;
    if (t >= n4) return;
    float4 v = ((const float4*)in)[t];
    if (res) {
        float4 r = ((const float4*)res)[t];
        v.x += r.x; v.y += r.y; v.z += r.z; v.w += r.w;
    }
    v.x = v.x > 0.f ? v.x : expm1f(v.x);
    v.y = v.y > 0.f ? v.y : expm1f(v.y);
    v.z = v.z > 0.f ? v.z : expm1f(v.z);
    v.w = v.w > 0.f ? v.w : expm1f(v.w);
    ((float4*)out)[t] = v;
}

__global__ void final_add_k(const float* __restrict__ a, const float* __restrict__ b,
                            float* __restrict__ out, int n4) {
    int t = blockIdx.x * blockDim.x + threadIdx.x;
    if (t >= n4) return;
    float4 x = ((const float4*)a)[t];
    float4 y = ((const float4*)b)[t];
    x.x += y.x; x.y += y.y; x.z += y.z; x.w += y.w;
    ((float4*)out)[t] = x;
}

// ---------------- host ----------------

extern "C" void kernel_launch(void* const* d_in, const int* in_sizes, int n_in,
                              void* d_out, int out_size, void* d_ws, size_t ws_size,
                              hipStream_t stream) {
    const float* x0 = (const float*)d_in[0];
    const float* x1 = (const float*)d_in[1];
    const float* x2 = (const float*)d_in[2];
    const int* src  = (const int*)d_in[3];
    const int* dst  = (const int*)d_in[4];
    const int* et   = (const int*)d_in[5];
    const float* W0 = (const float*)d_in[6];  const float* b0 = (const float*)d_in[7];
    const float* W1 = (const float*)d_in[8];  const float* b1 = (const float*)d_in[9];
    const float* W2 = (const float*)d_in[10]; const float* b2 = (const float*)d_in[11];
    const float* Wg0 = (const float*)d_in[12]; const float* etab0 = (const float*)d_in[13];
    const float* We0 = (const float*)d_in[14]; const float* al0 = (const float*)d_in[15];
    const float* ar0 = (const float*)d_in[16]; const float* ae0 = (const float*)d_in[17];
    const float* Wg1 = (const float*)d_in[18]; const float* etab1 = (const float*)d_in[19];
    const float* We1 = (const float*)d_in[20]; const float* al1 = (const float*)d_in[21];
    const float* ar1 = (const float*)d_in[22]; const float* ae1 = (const float*)d_in[23];
    const float* Wg2 = (const float*)d_in[24]; const float* etab2 = (const float*)d_in[25];
    const float* We2 = (const float*)d_in[26]; const float* al2 = (const float*)d_in[27];
    const float* ar2 = (const float*)d_in[28]; const float* ae2 = (const float*)d_in[29];
    const float* resW2 = (const float*)d_in[30];
    float* outp = (float*)d_out;

    char* p = (char*)d_ws;
    auto alloc = [&](size_t bytes) -> void* {
        void* r = (void*)p;
        p += (bytes + 255) & ~(size_t)255;
        return r;
    };
    float* h0   = (float*)alloc((size_t)NN * 64 * 4);
    float* feat = (float*)alloc((size_t)NN * 256 * 4);
    float* bufA = (float*)alloc((size_t)NN * 256 * 4);   // out0 -> h1
    float* bufB = (float*)alloc((size_t)NN * 256 * 4);   // out1 -> h2
    float* el   = (float*)alloc((size_t)NN * 4 * 4);
    float* er   = (float*)alloc((size_t)NN * 4 * 4);
    float* lg   = (float*)alloc((size_t)EE * 4 * 4);
    float* a0   = (float*)alloc((size_t)EE * 4 * 4);
    float* es   = (float*)alloc(96 * 4);
    float* out2 = (float*)alloc((size_t)NN * 16 * 4);
    float* res2 = (float*)alloc((size_t)NN * 16 * 4);
    int* rowstart = (int*)alloc((size_t)(NN + 1) * 4);
    int* deg      = (int*)alloc((size_t)NN * 4);
    int* cursor   = (int*)alloc((size_t)NN * 4);
    int* ebuf     = (int*)alloc((size_t)EE * 4);
    int* csrc     = (int*)alloc((size_t)EE * 4);

    const int EB = (EE + 255) / 256;        // 3125
    const int NHB = (NN * 4 + 255) / 256;   // 782

    // CSR build (per launch; ws is re-poisoned every call)
    hipMemsetAsync(deg, 0, (size_t)NN * 4, stream);
    hist_kernel<<<EB, 256, 0, stream>>>(dst, deg, EE);
    scan_excl_kernel<<<1, 1024, 0, stream>>>(deg, rowstart, NN);
    hipMemcpyAsync(cursor, rowstart, (size_t)NN * 4, hipMemcpyDeviceToDevice, stream);
    scatter_kernel<<<EB, 256, 0, stream>>>(src, dst, cursor, ebuf, csrc, EE);

    // es tables
    es_table_kernel<<<32, 64, 0, stream>>>(etab0, We0, ae0, es + 0, 4);
    es_table_kernel<<<32, 64, 0, stream>>>(etab1, We1, ae1, es + 32, 4);
    es_table_kernel<<<8, 64, 0, stream>>>(etab2, We2, ae2, es + 64, 1);

    // input projections -> h0 [N,64]
    gemm_nt<64, 64, 32, 4, 4><<<dim3((N0 + 63) / 64, 1), 256, 0, stream>>>(x0, W0, b0, h0, N0, 64, 128);
    gemm_nt<64, 64, 32, 4, 4><<<dim3((N1 + 63) / 64, 1), 256, 0, stream>>>(x1, W1, b1, h0 + (size_t)N0 * 64, N1, 64, 64);
    gemm_nt<64, 64, 32, 4, 4><<<dim3((N2 + 63) / 64, 1), 256, 0, stream>>>(x2, W2, b2, h0 + (size_t)(N0 + N1) * 64, N2, 64, 32);

    // ---- GAT layer 0 ----
    gemm_nt<128, 128, 16, 8, 8><<<dim3((NN + 127) / 128, 2), 256, 0, stream>>>(h0, Wg0, nullptr, feat, NN, 256, 64);
    node_elr<4, 64><<<NHB, 256, 0, stream>>>(feat, al0, ar0, el, er, NN);
    edge_logits_h4<<<EB, 256, 0, stream>>>(src, dst, et, el, er, es + 0, lg, EE);
    edge_softmax_k<4><<<NHB, 256, 0, stream>>>(rowstart, ebuf, lg, (const float*)nullptr, a0, NN);
    aggregate256<<<(NN + 3) / 4, 256, 0, stream>>>(rowstart, ebuf, csrc, a0, feat, bufA, NN);
    elu_res_k<<<(NN * 64 + 255) / 256, 256, 0, stream>>>(bufA, (const float*)nullptr, bufA, NN * 64);

    // ---- GAT layer 1 ----
    gemm_nt<128, 128, 16, 8, 8><<<dim3((NN + 127) / 128, 2), 256, 0, stream>>>(bufA, Wg1, nullptr, feat, NN, 256, 256);
    node_elr<4, 64><<<NHB, 256, 0, stream>>>(feat, al1, ar1, el, er, NN);
    edge_logits_h4<<<EB, 256, 0, stream>>>(src, dst, et, el, er, es + 32, lg, EE);
    edge_softmax_k<4><<<NHB, 256, 0, stream>>>(rowstart, ebuf, lg, a0, lg, NN);
    aggregate256<<<(NN + 3) / 4, 256, 0, stream>>>(rowstart, ebuf, csrc, lg, feat, bufB, NN);
    elu_res_k<<<(NN * 64 + 255) / 256, 256, 0, stream>>>(bufB, bufA, bufB, NN * 64);

    // ---- GAT layer 2 (H=1, C=16, linear residual, no act) ----
    gemm_feat2<<<(NN + 7) / 8, 256, 0, stream>>>(bufB, Wg2, resW2, feat, res2, NN);
    node_elr<1, 16><<<(NN + 255) / 256, 256, 0, stream>>>(feat, al2, ar2, el, er, NN);
    edge_logits_h1<<<EB, 256, 0, stream>>>(src, dst, et, el, er, es + 64, lg, EE);
    edge_softmax_k<1><<<(NN + 255) / 256, 256, 0, stream>>>(rowstart, ebuf, lg, (const float*)nullptr, lg, NN);
    aggregate16<<<(NN * 4 + 255) / 256, 256, 0, stream>>>(rowstart, ebuf, csrc, lg, feat, out2, NN);
    final_add_k<<<(NN * 4 + 255) / 256, 256, 0, stream>>>(out2, res2, outp, NN * 4);
}

// Round 2
// 822.080 us; speedup vs baseline: 1.5323x; 1.5323x over previous
//
#include <hip/hip_runtime.h>
#include <math.h>

#define N0 20000
#define N1 15000
#define N2 15000
#define NN 50000          // total nodes
#define EE 800000         // edges
#define SLOPE 0.2f
#define ALPHA 0.05f

// ---------------- CSR build ----------------

__global__ void hist_kernel(const int* __restrict__ dst, int* __restrict__ deg, int E_) {
    int e = blockIdx.x * blockDim.x + threadIdx.x;
    if (e < E_) atomicAdd(&deg[dst[e]], 1);
}

__global__ __launch_bounds__(256) void block_sum_kernel(const int* __restrict__ deg,
                                                        int* __restrict__ bsum, int n) {
    int i = blockIdx.x * 256 + threadIdx.x;
    int v = (i < n) ? deg[i] : 0;
    #pragma unroll
    for (int off = 32; off > 0; off >>= 1) v += __shfl_down(v, off);
    __shared__ int sh[4];
    if ((threadIdx.x & 63) == 0) sh[threadIdx.x >> 6] = v;
    __syncthreads();
    if (threadIdx.x == 0) bsum[blockIdx.x] = sh[0] + sh[1] + sh[2] + sh[3];
}

__global__ __launch_bounds__(256) void scan_bsum_kernel(int* __restrict__ bsum, int nb) {
    __shared__ int sh[256];
    int tid = threadIdx.x;
    int v = (tid < nb) ? bsum[tid] : 0;
    sh[tid] = v;
    __syncthreads();
    #pragma unroll
    for (int off = 1; off < 256; off <<= 1) {
        int t = (tid >= off) ? sh[tid - off] : 0;
        __syncthreads();
        sh[tid] += t;
        __syncthreads();
    }
    if (tid < nb) bsum[tid] = sh[tid] - v;   // exclusive
}

__global__ __launch_bounds__(256) void scan_out_kernel(const int* __restrict__ deg,
                                                       const int* __restrict__ boff,
                                                       int* __restrict__ rowstart,
                                                       int* __restrict__ cursor, int n) {
    __shared__ int sh[256];
    int tid = threadIdx.x;
    int i = blockIdx.x * 256 + tid;
    int v = (i < n) ? deg[i] : 0;
    sh[tid] = v;
    __syncthreads();
    #pragma unroll
    for (int off = 1; off < 256; off <<= 1) {
        int t = (tid >= off) ? sh[tid - off] : 0;
        __syncthreads();
        sh[tid] += t;
        __syncthreads();
    }
    int excl = sh[tid] - v + boff[blockIdx.x];
    if (i < n) { rowstart[i] = excl; cursor[i] = excl; }
    if (i == n - 1) rowstart[n] = excl + v;
}

__global__ void scatter_kernel(const int* __restrict__ src, const int* __restrict__ dst,
                               const int* __restrict__ et, int* __restrict__ cursor,
                               int* __restrict__ csrc, int* __restrict__ cdst,
                               int* __restrict__ cet, int E_) {
    int e = blockIdx.x * blockDim.x + threadIdx.x;
    if (e >= E_) return;
    int d = dst[e];
    int p = atomicAdd(&cursor[d], 1);
    csrc[p] = src[e];
    cdst[p] = d;
    cet[p] = et[e];
}

// ---------------- es table: es[t,h] = sum_j ae[h,j] * dot(We[h*64+j,:], etab[t,:]) ----------------

__global__ void es_table_kernel(const float* __restrict__ etab, const float* __restrict__ We,
                                const float* __restrict__ ae, float* __restrict__ es, int H) {
    int b = blockIdx.x;
    int t = b / H, h = b % H;
    int j = threadIdx.x;   // 0..63
    const float* w = We + (size_t)(h * 64 + j) * 64;
    const float* e = etab + t * 64;
    float s = 0.f;
    #pragma unroll
    for (int k = 0; k < 64; k += 4) {
        float4 wv = *(const float4*)(w + k);
        float4 ev = *(const float4*)(e + k);
        s += wv.x * ev.x + wv.y * ev.y + wv.z * ev.z + wv.w * ev.w;
    }
    s *= ae[h * 64 + j];
    #pragma unroll
    for (int off = 32; off > 0; off >>= 1) s += __shfl_down(s, off);
    if (j == 0) es[t * H + h] = s;
}

// ---------------- weight pack for layer 2: [Wg2(16x256) ; resW2(16x256)] -> [32,256] ----------------

__global__ void pack_w2(const float* __restrict__ Wg, const float* __restrict__ Wr,
                        float* __restrict__ out) {
    int t = blockIdx.x * 256 + threadIdx.x;
    if (t < 8192) out[t] = (t < 4096) ? Wg[t] : Wr[t - 4096];
}

// ---------------- tiled fp32 GEMM: C[m,n] = sum_k A[m,k]*B[n,k] (+bias[n]) ----------------

template<int BM, int BN, int BK, int TM, int TN>
__global__ __launch_bounds__(256) void gemm_nt(const float* __restrict__ A, const float* __restrict__ B,
                                               const float* __restrict__ bias, float* __restrict__ C,
                                               int M, int N, int K) {
    constexpr int BMP = BM + 4, BNP = BN + 4;
    __shared__ float As[BK * BMP];
    __shared__ float Bs[BK * BNP];
    const int tid = threadIdx.x;
    const int m0 = blockIdx.x * BM;
    const int n0 = blockIdx.y * BN;
    const int tx = tid % (BN / TN);
    const int ty = tid / (BN / TN);
    float acc[TM][TN] = {};
    constexpr int LDA = (BM * BK) / (256 * 4);
    constexpr int LDB = (BN * BK) / (256 * 4);
    for (int k0 = 0; k0 < K; k0 += BK) {
        #pragma unroll
        for (int l = 0; l < LDA; l++) {
            int idx = (tid + l * 256) * 4;
            int row = idx / BK, col = idx % BK;
            int gr = m0 + row; if (gr >= M) gr = M - 1;
            float4 v = *(const float4*)(A + (size_t)gr * K + k0 + col);
            As[(col + 0) * BMP + row] = v.x;
            As[(col + 1) * BMP + row] = v.y;
            As[(col + 2) * BMP + row] = v.z;
            As[(col + 3) * BMP + row] = v.w;
        }
        #pragma unroll
        for (int l = 0; l < LDB; l++) {
            int idx = (tid + l * 256) * 4;
            int row = idx / BK, col = idx % BK;
            int gn = n0 + row;   // N % BN == 0 for all our launches
            float4 v = *(const float4*)(B + (size_t)gn * K + k0 + col);
            Bs[(col + 0) * BNP + row] = v.x;
            Bs[(col + 1) * BNP + row] = v.y;
            Bs[(col + 2) * BNP + row] = v.z;
            Bs[(col + 3) * BNP + row] = v.w;
        }
        __syncthreads();
        #pragma unroll
        for (int k = 0; k < BK; k++) {
            float a[TM], b[TN];
            #pragma unroll
            for (int i = 0; i < TM; i += 4) {
                float4 v = *(const float4*)(&As[k * BMP + ty * TM + i]);
                a[i] = v.x; a[i+1] = v.y; a[i+2] = v.z; a[i+3] = v.w;
            }
            #pragma unroll
            for (int j = 0; j < TN; j += 4) {
                float4 v = *(const float4*)(&Bs[k * BNP + tx * TN + j]);
                b[j] = v.x; b[j+1] = v.y; b[j+2] = v.z; b[j+3] = v.w;
            }
            #pragma unroll
            for (int i = 0; i < TM; i++)
                #pragma unroll
                for (int j = 0; j < TN; j++)
                    acc[i][j] = fmaf(a[i], b[j], acc[i][j]);
        }
        __syncthreads();
    }
    #pragma unroll
    for (int i = 0; i < TM; i++) {
        int m = m0 + ty * TM + i;
        if (m < M) {
            #pragma unroll
            for (int j = 0; j < TN; j += 4) {
                int n = n0 + tx * TN + j;
                float4 v;
                v.x = acc[i][j]; v.y = acc[i][j+1]; v.z = acc[i][j+2]; v.w = acc[i][j+3];
                if (bias) { v.x += bias[n]; v.y += bias[n+1]; v.z += bias[n+2]; v.w += bias[n+3]; }
                *(float4*)(C + (size_t)m * N + n) = v;
            }
        }
    }
}

// ---------------- per-node el/er ----------------

template<int H, int D, int STRIDE>
__global__ void node_elr(const float* __restrict__ feat, const float* __restrict__ al,
                         const float* __restrict__ ar, float* __restrict__ el,
                         float* __restrict__ er, int nN) {
    int t = blockIdx.x * blockDim.x + threadIdx.x;
    if (t >= nN * H) return;
    int n = t / H, h = t % H;
    const float* f = feat + (size_t)n * STRIDE + h * D;
    const float* a = al + h * D;
    const float* r = ar + h * D;
    float sl = 0.f, sr = 0.f;
    #pragma unroll
    for (int j = 0; j < D; j += 4) {
        float4 fv = *(const float4*)(f + j);
        float4 av = *(const float4*)(a + j);
        float4 rv = *(const float4*)(r + j);
        sl += fv.x * av.x + fv.y * av.y + fv.z * av.z + fv.w * av.w;
        sr += fv.x * rv.x + fv.y * rv.y + fv.z * rv.z + fv.w * rv.w;
    }
    el[t] = sl; er[t] = sr;
}

// ---------------- edge logits (CSR order) ----------------

__global__ void edge_logits_h4(const int* __restrict__ csrc, const int* __restrict__ cdst,
                               const int* __restrict__ cet, const float* __restrict__ el,
                               const float* __restrict__ er, const float* __restrict__ es,
                               float* __restrict__ lg, int E_) {
    int i = blockIdx.x * blockDim.x + threadIdx.x;
    if (i >= E_) return;
    int s = csrc[i], d = cdst[i], t = cet[i];
    float4 a = *(const float4*)(el + s * 4);
    float4 b = *(const float4*)(er + d * 4);
    float4 c = *(const float4*)(es + t * 4);
    float4 r;
    float v;
    v = a.x + b.x + c.x; r.x = v > 0.f ? v : SLOPE * v;
    v = a.y + b.y + c.y; r.y = v > 0.f ? v : SLOPE * v;
    v = a.z + b.z + c.z; r.z = v > 0.f ? v : SLOPE * v;
    v = a.w + b.w + c.w; r.w = v > 0.f ? v : SLOPE * v;
    *(float4*)(lg + (size_t)i * 4) = r;
}

__global__ void edge_logits_h1(const int* __restrict__ csrc, const int* __restrict__ cdst,
                               const int* __restrict__ cet, const float* __restrict__ el,
                               const float* __restrict__ er, const float* __restrict__ es,
                               float* __restrict__ lg, int E_) {
    int i = blockIdx.x * blockDim.x + threadIdx.x;
    if (i >= E_) return;
    float v = el[csrc[i]] + er[cdst[i]] + es[cet[i]];
    lg[i] = v > 0.f ? v : SLOPE * v;
}

// ---------------- edge softmax over contiguous CSR segments ----------------

__global__ void edge_softmax4(const int* __restrict__ rowstart, const float* __restrict__ lg,
                              const float* __restrict__ a_prev, float* __restrict__ a_out, int nN) {
    int n = blockIdx.x * blockDim.x + threadIdx.x;
    if (n >= nN) return;
    int r0 = rowstart[n], r1 = rowstart[n + 1];
    float4 m = {-INFINITY, -INFINITY, -INFINITY, -INFINITY};
    for (int i = r0; i < r1; i++) {
        float4 v = ((const float4*)lg)[i];
        m.x = fmaxf(m.x, v.x); m.y = fmaxf(m.y, v.y);
        m.z = fmaxf(m.z, v.z); m.w = fmaxf(m.w, v.w);
    }
    float4 s = {0.f, 0.f, 0.f, 0.f};
    for (int i = r0; i < r1; i++) {
        float4 v = ((const float4*)lg)[i];
        float4 e;
        e.x = __expf(v.x - m.x); e.y = __expf(v.y - m.y);
        e.z = __expf(v.z - m.z); e.w = __expf(v.w - m.w);
        ((float4*)a_out)[i] = e;   // a_out may alias lg; thread owns this range
        s.x += e.x; s.y += e.y; s.z += e.z; s.w += e.w;
    }
    float4 inv;
    inv.x = 1.f / (s.x + 1e-9f); inv.y = 1.f / (s.y + 1e-9f);
    inv.z = 1.f / (s.z + 1e-9f); inv.w = 1.f / (s.w + 1e-9f);
    for (int i = r0; i < r1; i++) {
        float4 a = ((const float4*)a_out)[i];
        a.x *= inv.x; a.y *= inv.y; a.z *= inv.z; a.w *= inv.w;
        if (a_prev) {
            float4 p = ((const float4*)a_prev)[i];
            a.x = a.x * (1.f - ALPHA) + ALPHA * p.x;
            a.y = a.y * (1.f - ALPHA) + ALPHA * p.y;
            a.z = a.z * (1.f - ALPHA) + ALPHA * p.z;
            a.w = a.w * (1.f - ALPHA) + ALPHA * p.w;
        }
        ((float4*)a_out)[i] = a;
    }
}

__global__ void edge_softmax1(const int* __restrict__ rowstart, float* __restrict__ lg, int nN) {
    int n = blockIdx.x * blockDim.x + threadIdx.x;
    if (n >= nN) return;
    int r0 = rowstart[n], r1 = rowstart[n + 1];
    float m = -INFINITY;
    for (int i = r0; i < r1; i++) m = fmaxf(m, lg[i]);
    float s = 0.f;
    for (int i = r0; i < r1; i++) {
        float v = __expf(lg[i] - m);
        lg[i] = v;
        s += v;
    }
    float inv = 1.f / (s + 1e-9f);
    for (int i = r0; i < r1; i++) lg[i] *= inv;
}

// ---------------- aggregation: one wave per dst (H=4, D=64 -> 256 floats) ----------------
// fused: optional residual add + optional ELU

__global__ __launch_bounds__(256) void aggregate256(const int* __restrict__ rowstart,
                                                    const int* __restrict__ csrc,
                                                    const float* __restrict__ a,
                                                    const float* __restrict__ feat,
                                                    const float* __restrict__ res,
                                                    float* __restrict__ out, int nN) {
    int n = blockIdx.x * 4 + (threadIdx.x >> 6);
    int lane = threadIdx.x & 63;
    if (n >= nN) return;
    int r0 = rowstart[n], r1 = rowstart[n + 1];
    int h = lane >> 4;
    float4 acc = {0.f, 0.f, 0.f, 0.f};
    for (int i = r0; i < r1; i++) {
        int s = csrc[i];
        float av = a[(size_t)i * 4 + h];
        float4 f = *(const float4*)(feat + (size_t)s * 256 + lane * 4);
        acc.x += av * f.x; acc.y += av * f.y; acc.z += av * f.z; acc.w += av * f.w;
    }
    if (res) {
        float4 r = *(const float4*)(res + (size_t)n * 256 + lane * 4);
        acc.x += r.x; acc.y += r.y; acc.z += r.z; acc.w += r.w;
    }
    acc.x = acc.x > 0.f ? acc.x : expm1f(acc.x);
    acc.y = acc.y > 0.f ? acc.y : expm1f(acc.y);
    acc.z = acc.z > 0.f ? acc.z : expm1f(acc.z);
    acc.w = acc.w > 0.f ? acc.w : expm1f(acc.w);
    *(float4*)(out + (size_t)n * 256 + lane * 4) = acc;
}

// layer 2: H=1, 16 outputs per dst -> 4 lanes per dst; fused residual (stride-32 pack, offset 16)
__global__ __launch_bounds__(256) void aggregate16(const int* __restrict__ rowstart,
                                                   const int* __restrict__ csrc,
                                                   const float* __restrict__ a,
                                                   const float* __restrict__ cpack,
                                                   float* __restrict__ out, int nN) {
    int t = blockIdx.x * blockDim.x + threadIdx.x;
    int n = t >> 2, l = t & 3;
    if (n >= nN) return;
    int r0 = rowstart[n], r1 = rowstart[n + 1];
    float4 acc = {0.f, 0.f, 0.f, 0.f};
    for (int i = r0; i < r1; i++) {
        int s = csrc[i];
        float av = a[i];
        float4 f = *(const float4*)(cpack + (size_t)s * 32 + l * 4);
        acc.x += av * f.x; acc.y += av * f.y; acc.z += av * f.z; acc.w += av * f.w;
    }
    float4 r = *(const float4*)(cpack + (size_t)n * 32 + 16 + l * 4);
    acc.x += r.x; acc.y += r.y; acc.z += r.z; acc.w += r.w;
    *(float4*)(out + (size_t)n * 16 + l * 4) = acc;
}

// ---------------- host ----------------

extern "C" void kernel_launch(void* const* d_in, const int* in_sizes, int n_in,
                              void* d_out, int out_size, void* d_ws, size_t ws_size,
                              hipStream_t stream) {
    const float* x0 = (const float*)d_in[0];
    const float* x1 = (const float*)d_in[1];
    const float* x2 = (const float*)d_in[2];
    const int* src  = (const int*)d_in[3];
    const int* dst  = (const int*)d_in[4];
    const int* et   = (const int*)d_in[5];
    const float* W0 = (const float*)d_in[6];  const float* b0 = (const float*)d_in[7];
    const float* W1 = (const float*)d_in[8];  const float* b1 = (const float*)d_in[9];
    const float* W2 = (const float*)d_in[10]; const float* b2 = (const float*)d_in[11];
    const float* Wg0 = (const float*)d_in[12]; const float* etab0 = (const float*)d_in[13];
    const float* We0 = (const float*)d_in[14]; const float* al0 = (const float*)d_in[15];
    const float* ar0 = (const float*)d_in[16]; const float* ae0 = (const float*)d_in[17];
    const float* Wg1 = (const float*)d_in[18]; const float* etab1 = (const float*)d_in[19];
    const float* We1 = (const float*)d_in[20]; const float* al1 = (const float*)d_in[21];
    const float* ar1 = (const float*)d_in[22]; const float* ae1 = (const float*)d_in[23];
    const float* Wg2 = (const float*)d_in[24]; const float* etab2 = (const float*)d_in[25];
    const float* We2 = (const float*)d_in[26]; const float* al2 = (const float*)d_in[27];
    const float* ar2 = (const float*)d_in[28]; const float* ae2 = (const float*)d_in[29];
    const float* resW2 = (const float*)d_in[30];
    float* outp = (float*)d_out;

    char* p = (char*)d_ws;
    auto alloc = [&](size_t bytes) -> void* {
        void* r = (void*)p;
        p += (bytes + 255) & ~(size_t)255;
        return r;
    };
    float* h0    = (float*)alloc((size_t)NN * 64 * 4);
    float* feat  = (float*)alloc((size_t)NN * 256 * 4);
    float* bufA  = (float*)alloc((size_t)NN * 256 * 4);
    float* bufB  = (float*)alloc((size_t)NN * 256 * 4);
    float* el    = (float*)alloc((size_t)NN * 4 * 4);
    float* er    = (float*)alloc((size_t)NN * 4 * 4);
    float* lg    = (float*)alloc((size_t)EE * 4 * 4);
    float* a0    = (float*)alloc((size_t)EE * 4 * 4);
    float* es    = (float*)alloc(96 * 4);
    float* wpack = (float*)alloc(32 * 256 * 4);
    float* cpack = (float*)alloc((size_t)NN * 32 * 4);
    int* rowstart = (int*)alloc((size_t)(NN + 1) * 4);
    int* deg      = (int*)alloc((size_t)NN * 4);
    int* cursor   = (int*)alloc((size_t)NN * 4);
    int* bsum     = (int*)alloc(256 * 4);
    int* csrc     = (int*)alloc((size_t)EE * 4);
    int* cdst     = (int*)alloc((size_t)EE * 4);
    int* cet      = (int*)alloc((size_t)EE * 4);

    const int EB = (EE + 255) / 256;        // 3125
    const int NB = (NN + 255) / 256;        // 196
    const int NHB = (NN * 4 + 255) / 256;   // 782

    // CSR build
    hipMemsetAsync(deg, 0, (size_t)NN * 4, stream);
    hist_kernel<<<EB, 256, 0, stream>>>(dst, deg, EE);
    block_sum_kernel<<<NB, 256, 0, stream>>>(deg, bsum, NN);
    scan_bsum_kernel<<<1, 256, 0, stream>>>(bsum, NB);
    scan_out_kernel<<<NB, 256, 0, stream>>>(deg, bsum, rowstart, cursor, NN);
    scatter_kernel<<<EB, 256, 0, stream>>>(src, dst, et, cursor, csrc, cdst, cet, EE);

    // es tables + weight pack
    es_table_kernel<<<32, 64, 0, stream>>>(etab0, We0, ae0, es + 0, 4);
    es_table_kernel<<<32, 64, 0, stream>>>(etab1, We1, ae1, es + 32, 4);
    es_table_kernel<<<8, 64, 0, stream>>>(etab2, We2, ae2, es + 64, 1);
    pack_w2<<<32, 256, 0, stream>>>(Wg2, resW2, wpack);

    // input projections -> h0 [N,64]
    gemm_nt<64, 64, 32, 4, 4><<<dim3((N0 + 63) / 64, 1), 256, 0, stream>>>(x0, W0, b0, h0, N0, 64, 128);
    gemm_nt<64, 64, 32, 4, 4><<<dim3((N1 + 63) / 64, 1), 256, 0, stream>>>(x1, W1, b1, h0 + (size_t)N0 * 64, N1, 64, 64);
    gemm_nt<64, 64, 32, 4, 4><<<dim3((N2 + 63) / 64, 1), 256, 0, stream>>>(x2, W2, b2, h0 + (size_t)(N0 + N1) * 64, N2, 64, 32);

    // ---- GAT layer 0 ----
    gemm_nt<128, 128, 16, 8, 8><<<dim3((NN + 127) / 128, 2), 256, 0, stream>>>(h0, Wg0, nullptr, feat, NN, 256, 64);
    node_elr<4, 64, 256><<<NHB, 256, 0, stream>>>(feat, al0, ar0, el, er, NN);
    edge_logits_h4<<<EB, 256, 0, stream>>>(csrc, cdst, cet, el, er, es + 0, lg, EE);
    edge_softmax4<<<NB, 256, 0, stream>>>(rowstart, lg, (const float*)nullptr, a0, NN);
    aggregate256<<<(NN + 3) / 4, 256, 0, stream>>>(rowstart, csrc, a0, feat, (const float*)nullptr, bufA, NN);

    // ---- GAT layer 1 ----
    gemm_nt<128, 128, 16, 8, 8><<<dim3((NN + 127) / 128, 2), 256, 0, stream>>>(bufA, Wg1, nullptr, feat, NN, 256, 256);
    node_elr<4, 64, 256><<<NHB, 256, 0, stream>>>(feat, al1, ar1, el, er, NN);
    edge_logits_h4<<<EB, 256, 0, stream>>>(csrc, cdst, cet, el, er, es + 32, lg, EE);
    edge_softmax4<<<NB, 256, 0, stream>>>(rowstart, lg, a0, lg, NN);
    aggregate256<<<(NN + 3) / 4, 256, 0, stream>>>(rowstart, csrc, lg, feat, bufA, bufB, NN);

    // ---- GAT layer 2 (H=1, C=16, linear residual, no act) ----
    gemm_nt<128, 32, 32, 4, 4><<<dim3((NN + 127) / 128, 1), 256, 0, stream>>>(bufB, wpack, nullptr, cpack, NN, 32, 256);
    node_elr<1, 16, 32><<<NB, 256, 0, stream>>>(cpack, al2, ar2, el, er, NN);
    edge_logits_h1<<<EB, 256, 0, stream>>>(csrc, cdst, cet, el, er, es + 64, lg, EE);
    edge_softmax1<<<NB, 256, 0, stream>>>(rowstart, lg, NN);
    aggregate16<<<NHB, 256, 0, stream>>>(rowstart, csrc, lg, cpack, outp, NN);
}

// Round 3
// 689.924 us; speedup vs baseline: 1.8258x; 1.1916x over previous
//
#include <hip/hip_runtime.h>
#include <math.h>

#define N0 20000
#define N1 15000
#define N2 15000
#define NN 50000          // total nodes
#define EE 800000         // edges
#define SLOPE 0.2f
#define ALPHA 0.05f

typedef _Float16 h8 __attribute__((ext_vector_type(8)));
typedef _Float16 h4 __attribute__((ext_vector_type(4)));
typedef float f4v __attribute__((ext_vector_type(4)));

// ---------------- CSR build ----------------

__global__ void hist_kernel(const int* __restrict__ dst, int* __restrict__ deg, int E_) {
    int e = blockIdx.x * blockDim.x + threadIdx.x;
    if (e < E_) atomicAdd(&deg[dst[e]], 1);
}

__global__ __launch_bounds__(256) void block_sum_kernel(const int* __restrict__ deg,
                                                        int* __restrict__ bsum, int n) {
    int i = blockIdx.x * 256 + threadIdx.x;
    int v = (i < n) ? deg[i] : 0;
    #pragma unroll
    for (int off = 32; off > 0; off >>= 1) v += __shfl_down(v, off);
    __shared__ int sh[4];
    if ((threadIdx.x & 63) == 0) sh[threadIdx.x >> 6] = v;
    __syncthreads();
    if (threadIdx.x == 0) bsum[blockIdx.x] = sh[0] + sh[1] + sh[2] + sh[3];
}

__global__ __launch_bounds__(256) void scan_bsum_kernel(int* __restrict__ bsum, int nb) {
    __shared__ int sh[256];
    int tid = threadIdx.x;
    int v = (tid < nb) ? bsum[tid] : 0;
    sh[tid] = v;
    __syncthreads();
    #pragma unroll
    for (int off = 1; off < 256; off <<= 1) {
        int t = (tid >= off) ? sh[tid - off] : 0;
        __syncthreads();
        sh[tid] += t;
        __syncthreads();
    }
    if (tid < nb) bsum[tid] = sh[tid] - v;   // exclusive
}

__global__ __launch_bounds__(256) void scan_out_kernel(const int* __restrict__ deg,
                                                       const int* __restrict__ boff,
                                                       int* __restrict__ rowstart,
                                                       int* __restrict__ cursor, int n) {
    __shared__ int sh[256];
    int tid = threadIdx.x;
    int i = blockIdx.x * 256 + tid;
    int v = (i < n) ? deg[i] : 0;
    sh[tid] = v;
    __syncthreads();
    #pragma unroll
    for (int off = 1; off < 256; off <<= 1) {
        int t = (tid >= off) ? sh[tid - off] : 0;
        __syncthreads();
        sh[tid] += t;
        __syncthreads();
    }
    int excl = sh[tid] - v + boff[blockIdx.x];
    if (i < n) { rowstart[i] = excl; cursor[i] = excl; }
    if (i == n - 1) rowstart[n] = excl + v;
}

__global__ void scatter_kernel(const int* __restrict__ src, const int* __restrict__ dst,
                               const int* __restrict__ et, int* __restrict__ cursor,
                               int* __restrict__ csrc, int* __restrict__ cdst,
                               int* __restrict__ cet, int E_) {
    int e = blockIdx.x * blockDim.x + threadIdx.x;
    if (e >= E_) return;
    int d = dst[e];
    int p = atomicAdd(&cursor[d], 1);
    csrc[p] = src[e];
    cdst[p] = d;
    cet[p] = et[e];
}

// ---------------- es table ----------------

__global__ void es_table_kernel(const float* __restrict__ etab, const float* __restrict__ We,
                                const float* __restrict__ ae, float* __restrict__ es, int H) {
    int b = blockIdx.x;
    int t = b / H, h = b % H;
    int j = threadIdx.x;   // 0..63
    const float* w = We + (size_t)(h * 64 + j) * 64;
    const float* e = etab + t * 64;
    float s = 0.f;
    #pragma unroll
    for (int k = 0; k < 64; k += 4) {
        float4 wv = *(const float4*)(w + k);
        float4 ev = *(const float4*)(e + k);
        s += wv.x * ev.x + wv.y * ev.y + wv.z * ev.z + wv.w * ev.w;
    }
    s *= ae[h * 64 + j];
    #pragma unroll
    for (int off = 32; off > 0; off >>= 1) s += __shfl_down(s, off);
    if (j == 0) es[t * H + h] = s;
}

// ---------------- weight pack for layer 2 (fp16): [Wg2(16x256) ; resW2(16x256)] ----------------

__global__ void pack_w2h(const float* __restrict__ Wg, const float* __restrict__ Wr,
                         _Float16* __restrict__ out) {
    int t = blockIdx.x * 256 + threadIdx.x;
    if (t < 8192) out[t] = (_Float16)((t < 4096) ? Wg[t] : Wr[t - 4096]);
}

// ---------------- fp32 -> fp16 converts (8 arrays, one launch) ----------------

__global__ void f2h8(const float* s0, _Float16* d0, int n0,
                     const float* s1, _Float16* d1, int n1,
                     const float* s2, _Float16* d2, int n2,
                     const float* s3, _Float16* d3, int n3,
                     const float* s4, _Float16* d4, int n4,
                     const float* s5, _Float16* d5, int n5,
                     const float* s6, _Float16* d6, int n6,
                     const float* s7, _Float16* d7, int n7) {
    int t = blockIdx.x * 256 + threadIdx.x;
    if (t < n0) { d0[t] = (_Float16)s0[t]; return; } t -= n0;
    if (t < n1) { d1[t] = (_Float16)s1[t]; return; } t -= n1;
    if (t < n2) { d2[t] = (_Float16)s2[t]; return; } t -= n2;
    if (t < n3) { d3[t] = (_Float16)s3[t]; return; } t -= n3;
    if (t < n4) { d4[t] = (_Float16)s4[t]; return; } t -= n4;
    if (t < n5) { d5[t] = (_Float16)s5[t]; return; } t -= n5;
    if (t < n6) { d6[t] = (_Float16)s6[t]; return; } t -= n6;
    if (t < n7) { d7[t] = (_Float16)s7[t]; }
}

// ---------------- MFMA fp16 GEMM: C[m,n] = sum_k A[m,k]*B[n,k] (+bias) ----------------
// A [M,K] fp16, B [N,K] fp16 (weights, read via L1/L2 - no LDS), fp32 accumulate.
// Verified fragment mapping (16x16x32): A[m=lane&15][k=(lane>>4)*8+j],
// B[n=lane&15][k=(lane>>4)*8+j], D[row=(lane>>4)*4+r][col=lane&15].
// Wave tile: 32(M) x NT*16(N). Block: 4 waves -> 128 rows.

template<int NT>
__global__ __launch_bounds__(256) void gemm_mfma(const _Float16* __restrict__ A,
                                                 const _Float16* __restrict__ B,
                                                 const float* __restrict__ bias,
                                                 float* __restrict__ Cf,
                                                 _Float16* __restrict__ Ch,
                                                 int M, int N, int K) {
    const int wave = threadIdx.x >> 6;
    const int lane = threadIdx.x & 63;
    const int m_base = (blockIdx.x * 4 + wave) * 32;
    const int n_base = blockIdx.y * (NT * 16);
    const int row = lane & 15;
    const int kq = (lane >> 4) * 8;

    f4v acc[2][NT];
    #pragma unroll
    for (int i = 0; i < 2; i++)
        #pragma unroll
        for (int j = 0; j < NT; j++) {
            f4v z = {0.f, 0.f, 0.f, 0.f};
            acc[i][j] = z;
        }

    int r0 = m_base + row;      if (r0 >= M) r0 = M - 1;
    int r1 = m_base + 16 + row; if (r1 >= M) r1 = M - 1;
    const _Float16* a0p = A + (size_t)r0 * K + kq;
    const _Float16* a1p = A + (size_t)r1 * K + kq;
    const _Float16* bp  = B + (size_t)(n_base + row) * K + kq;

    for (int k = 0; k < K; k += 32) {
        h8 a0 = *(const h8*)(a0p + k);
        h8 a1 = *(const h8*)(a1p + k);
        #pragma unroll
        for (int j = 0; j < NT; j++) {
            h8 b = *(const h8*)(bp + (size_t)j * 16 * K + k);
            acc[0][j] = __builtin_amdgcn_mfma_f32_16x16x32_f16(a0, b, acc[0][j], 0, 0, 0);
            acc[1][j] = __builtin_amdgcn_mfma_f32_16x16x32_f16(a1, b, acc[1][j], 0, 0, 0);
        }
    }

    const int col = lane & 15;
    const int rb = (lane >> 4) * 4;
    #pragma unroll
    for (int ms = 0; ms < 2; ms++) {
        #pragma unroll
        for (int j = 0; j < NT; j++) {
            #pragma unroll
            for (int r = 0; r < 4; r++) {
                int m = m_base + ms * 16 + rb + r;
                if (m < M) {
                    int n = n_base + j * 16 + col;
                    float v = acc[ms][j][r];
                    if (bias) v += bias[n];
                    if (Cf) Cf[(size_t)m * N + n] = v;
                    if (Ch) Ch[(size_t)m * N + n] = (_Float16)v;
                }
            }
        }
    }
}

// ---------------- per-node el/er ----------------

// fp16 feat version (layers 0/1): feat [nN, 256] fp16, H=4, D=64
__global__ void node_elr_h(const _Float16* __restrict__ feat, const float* __restrict__ al,
                           const float* __restrict__ ar, float* __restrict__ el,
                           float* __restrict__ er, int nN) {
    int t = blockIdx.x * blockDim.x + threadIdx.x;
    if (t >= nN * 4) return;
    int n = t >> 2, h = t & 3;
    const _Float16* f = feat + (size_t)n * 256 + h * 64;
    const float* a = al + h * 64;
    const float* r = ar + h * 64;
    float sl = 0.f, sr = 0.f;
    #pragma unroll
    for (int j = 0; j < 64; j += 8) {
        h8 fv = *(const h8*)(f + j);
        #pragma unroll
        for (int q = 0; q < 8; q++) {
            float x = (float)fv[q];
            sl = fmaf(x, a[j + q], sl);
            sr = fmaf(x, r[j + q], sr);
        }
    }
    el[t] = sl; er[t] = sr;
}

// fp32 version (layer 2): feat [nN, 32] fp32 (cpack), H=1, D=16
__global__ void node_elr_f2(const float* __restrict__ feat, const float* __restrict__ al,
                            const float* __restrict__ ar, float* __restrict__ el,
                            float* __restrict__ er, int nN) {
    int t = blockIdx.x * blockDim.x + threadIdx.x;
    if (t >= nN) return;
    const float* f = feat + (size_t)t * 32;
    float sl = 0.f, sr = 0.f;
    #pragma unroll
    for (int j = 0; j < 16; j += 4) {
        float4 fv = *(const float4*)(f + j);
        float4 av = *(const float4*)(al + j);
        float4 rv = *(const float4*)(ar + j);
        sl += fv.x * av.x + fv.y * av.y + fv.z * av.z + fv.w * av.w;
        sr += fv.x * rv.x + fv.y * rv.y + fv.z * rv.z + fv.w * rv.w;
    }
    el[t] = sl; er[t] = sr;
}

// ---------------- edge logits (CSR order) ----------------

__global__ void edge_logits_h4(const int* __restrict__ csrc, const int* __restrict__ cdst,
                               const int* __restrict__ cet, const float* __restrict__ el,
                               const float* __restrict__ er, const float* __restrict__ es,
                               float* __restrict__ lg, int E_) {
    int i = blockIdx.x * blockDim.x + threadIdx.x;
    if (i >= E_) return;
    int s = csrc[i], d = cdst[i], t = cet[i];
    float4 a = *(const float4*)(el + s * 4);
    float4 b = *(const float4*)(er + d * 4);
    float4 c = *(const float4*)(es + t * 4);
    float4 r;
    float v;
    v = a.x + b.x + c.x; r.x = v > 0.f ? v : SLOPE * v;
    v = a.y + b.y + c.y; r.y = v > 0.f ? v : SLOPE * v;
    v = a.z + b.z + c.z; r.z = v > 0.f ? v : SLOPE * v;
    v = a.w + b.w + c.w; r.w = v > 0.f ? v : SLOPE * v;
    *(float4*)(lg + (size_t)i * 4) = r;
}

__global__ void edge_logits_h1(const int* __restrict__ csrc, const int* __restrict__ cdst,
                               const int* __restrict__ cet, const float* __restrict__ el,
                               const float* __restrict__ er, const float* __restrict__ es,
                               float* __restrict__ lg, int E_) {
    int i = blockIdx.x * blockDim.x + threadIdx.x;
    if (i >= E_) return;
    float v = el[csrc[i]] + er[cdst[i]] + es[cet[i]];
    lg[i] = v > 0.f ? v : SLOPE * v;
}

// ---------------- edge softmax over contiguous CSR segments ----------------

__global__ void edge_softmax4(const int* __restrict__ rowstart, const float* __restrict__ lg,
                              const float* __restrict__ a_prev, float* __restrict__ a_out, int nN) {
    int n = blockIdx.x * blockDim.x + threadIdx.x;
    if (n >= nN) return;
    int r0 = rowstart[n], r1 = rowstart[n + 1];
    float4 m = {-INFINITY, -INFINITY, -INFINITY, -INFINITY};
    for (int i = r0; i < r1; i++) {
        float4 v = ((const float4*)lg)[i];
        m.x = fmaxf(m.x, v.x); m.y = fmaxf(m.y, v.y);
        m.z = fmaxf(m.z, v.z); m.w = fmaxf(m.w, v.w);
    }
    float4 s = {0.f, 0.f, 0.f, 0.f};
    for (int i = r0; i < r1; i++) {
        float4 v = ((const float4*)lg)[i];
        float4 e;
        e.x = __expf(v.x - m.x); e.y = __expf(v.y - m.y);
        e.z = __expf(v.z - m.z); e.w = __expf(v.w - m.w);
        ((float4*)a_out)[i] = e;   // may alias lg; thread owns range
        s.x += e.x; s.y += e.y; s.z += e.z; s.w += e.w;
    }
    float4 inv;
    inv.x = 1.f / (s.x + 1e-9f); inv.y = 1.f / (s.y + 1e-9f);
    inv.z = 1.f / (s.z + 1e-9f); inv.w = 1.f / (s.w + 1e-9f);
    for (int i = r0; i < r1; i++) {
        float4 a = ((const float4*)a_out)[i];
        a.x *= inv.x; a.y *= inv.y; a.z *= inv.z; a.w *= inv.w;
        if (a_prev) {
            float4 p = ((const float4*)a_prev)[i];
            a.x = a.x * (1.f - ALPHA) + ALPHA * p.x;
            a.y = a.y * (1.f - ALPHA) + ALPHA * p.y;
            a.z = a.z * (1.f - ALPHA) + ALPHA * p.z;
            a.w = a.w * (1.f - ALPHA) + ALPHA * p.w;
        }
        ((float4*)a_out)[i] = a;
    }
}

__global__ void edge_softmax1(const int* __restrict__ rowstart, float* __restrict__ lg, int nN) {
    int n = blockIdx.x * blockDim.x + threadIdx.x;
    if (n >= nN) return;
    int r0 = rowstart[n], r1 = rowstart[n + 1];
    float m = -INFINITY;
    for (int i = r0; i < r1; i++) m = fmaxf(m, lg[i]);
    float s = 0.f;
    for (int i = r0; i < r1; i++) {
        float v = __expf(lg[i] - m);
        lg[i] = v;
        s += v;
    }
    float inv = 1.f / (s + 1e-9f);
    for (int i = r0; i < r1; i++) lg[i] *= inv;
}

// ---------------- aggregation: one wave per dst, fp16 feat gather ----------------
// fused residual (fp32) + ELU; writes fp32 and/or fp16 outputs

__global__ __launch_bounds__(256) void aggregate256(const int* __restrict__ rowstart,
                                                    const int* __restrict__ csrc,
                                                    const float* __restrict__ a,
                                                    const _Float16* __restrict__ feat,
                                                    const float* __restrict__ res,
                                                    float* __restrict__ outf,
                                                    _Float16* __restrict__ outh, int nN) {
    int n = blockIdx.x * 4 + (threadIdx.x >> 6);
    int lane = threadIdx.x & 63;
    if (n >= nN) return;
    int r0 = rowstart[n], r1 = rowstart[n + 1];
    int h = lane >> 4;
    float4 acc = {0.f, 0.f, 0.f, 0.f};
    for (int i = r0; i < r1; i++) {
        int s = csrc[i];
        float av = a[(size_t)i * 4 + h];
        h4 f = *(const h4*)(feat + (size_t)s * 256 + lane * 4);
        acc.x = fmaf(av, (float)f[0], acc.x);
        acc.y = fmaf(av, (float)f[1], acc.y);
        acc.z = fmaf(av, (float)f[2], acc.z);
        acc.w = fmaf(av, (float)f[3], acc.w);
    }
    if (res) {
        float4 r = *(const float4*)(res + (size_t)n * 256 + lane * 4);
        acc.x += r.x; acc.y += r.y; acc.z += r.z; acc.w += r.w;
    }
    acc.x = acc.x > 0.f ? acc.x : expm1f(acc.x);
    acc.y = acc.y > 0.f ? acc.y : expm1f(acc.y);
    acc.z = acc.z > 0.f ? acc.z : expm1f(acc.z);
    acc.w = acc.w > 0.f ? acc.w : expm1f(acc.w);
    if (outf) *(float4*)(outf + (size_t)n * 256 + lane * 4) = acc;
    if (outh) {
        h4 o;
        o[0] = (_Float16)acc.x; o[1] = (_Float16)acc.y;
        o[2] = (_Float16)acc.z; o[3] = (_Float16)acc.w;
        *(h4*)(outh + (size_t)n * 256 + lane * 4) = o;
    }
}

// layer 2: H=1, 16 outputs per dst -> 4 lanes per dst; fused residual (cpack stride 32, offset 16)
__global__ __launch_bounds__(256) void aggregate16(const int* __restrict__ rowstart,
                                                   const int* __restrict__ csrc,
                                                   const float* __restrict__ a,
                                                   const float* __restrict__ cpack,
                                                   float* __restrict__ out, int nN) {
    int t = blockIdx.x * blockDim.x + threadIdx.x;
    int n = t >> 2, l = t & 3;
    if (n >= nN) return;
    int r0 = rowstart[n], r1 = rowstart[n + 1];
    float4 acc = {0.f, 0.f, 0.f, 0.f};
    for (int i = r0; i < r1; i++) {
        int s = csrc[i];
        float av = a[i];
        float4 f = *(const float4*)(cpack + (size_t)s * 32 + l * 4);
        acc.x += av * f.x; acc.y += av * f.y; acc.z += av * f.z; acc.w += av * f.w;
    }
    float4 r = *(const float4*)(cpack + (size_t)n * 32 + 16 + l * 4);
    acc.x += r.x; acc.y += r.y; acc.z += r.z; acc.w += r.w;
    *(float4*)(out + (size_t)n * 16 + l * 4) = acc;
}

// ---------------- host ----------------

extern "C" void kernel_launch(void* const* d_in, const int* in_sizes, int n_in,
                              void* d_out, int out_size, void* d_ws, size_t ws_size,
                              hipStream_t stream) {
    const float* x0 = (const float*)d_in[0];
    const float* x1 = (const float*)d_in[1];
    const float* x2 = (const float*)d_in[2];
    const int* src  = (const int*)d_in[3];
    const int* dst  = (const int*)d_in[4];
    const int* et   = (const int*)d_in[5];
    const float* W0 = (const float*)d_in[6];  const float* b0 = (const float*)d_in[7];
    const float* W1 = (const float*)d_in[8];  const float* b1 = (const float*)d_in[9];
    const float* W2 = (const float*)d_in[10]; const float* b2 = (const float*)d_in[11];
    const float* Wg0 = (const float*)d_in[12]; const float* etab0 = (const float*)d_in[13];
    const float* We0 = (const float*)d_in[14]; const float* al0 = (const float*)d_in[15];
    const float* ar0 = (const float*)d_in[16]; const float* ae0 = (const float*)d_in[17];
    const float* Wg1 = (const float*)d_in[18]; const float* etab1 = (const float*)d_in[19];
    const float* We1 = (const float*)d_in[20]; const float* al1 = (const float*)d_in[21];
    const float* ar1 = (const float*)d_in[22]; const float* ae1 = (const float*)d_in[23];
    const float* Wg2 = (const float*)d_in[24]; const float* etab2 = (const float*)d_in[25];
    const float* We2 = (const float*)d_in[26]; const float* al2 = (const float*)d_in[27];
    const float* ar2 = (const float*)d_in[28]; const float* ae2 = (const float*)d_in[29];
    const float* resW2 = (const float*)d_in[30];
    float* outp = (float*)d_out;

    char* p = (char*)d_ws;
    auto alloc = [&](size_t bytes) -> void* {
        void* r = (void*)p;
        p += (bytes + 255) & ~(size_t)255;
        return r;
    };
    _Float16* x0h   = (_Float16*)alloc((size_t)N0 * 128 * 2);
    _Float16* x1h   = (_Float16*)alloc((size_t)N1 * 64 * 2);
    _Float16* x2h   = (_Float16*)alloc((size_t)N2 * 32 * 2);
    _Float16* W0h   = (_Float16*)alloc(64 * 128 * 2);
    _Float16* W1h   = (_Float16*)alloc(64 * 64 * 2);
    _Float16* W2h   = (_Float16*)alloc(64 * 32 * 2);
    _Float16* Wg0h  = (_Float16*)alloc(256 * 64 * 2);
    _Float16* Wg1h  = (_Float16*)alloc(256 * 256 * 2);
    _Float16* wpkh  = (_Float16*)alloc(32 * 256 * 2);
    _Float16* h0h   = (_Float16*)alloc((size_t)NN * 64 * 2);
    _Float16* feath = (_Float16*)alloc((size_t)NN * 256 * 2);
    _Float16* bufAh = (_Float16*)alloc((size_t)NN * 256 * 2);
    _Float16* bufBh = (_Float16*)alloc((size_t)NN * 256 * 2);
    float* bufA  = (float*)alloc((size_t)NN * 256 * 4);
    float* el    = (float*)alloc((size_t)NN * 4 * 4);
    float* er    = (float*)alloc((size_t)NN * 4 * 4);
    float* lg    = (float*)alloc((size_t)EE * 4 * 4);
    float* a0    = (float*)alloc((size_t)EE * 4 * 4);
    float* es    = (float*)alloc(96 * 4);
    float* cpack = (float*)alloc((size_t)NN * 32 * 4);
    int* rowstart = (int*)alloc((size_t)(NN + 1) * 4);
    int* deg      = (int*)alloc((size_t)NN * 4);
    int* cursor   = (int*)alloc((size_t)NN * 4);
    int* bsum     = (int*)alloc(256 * 4);
    int* csrc     = (int*)alloc((size_t)EE * 4);
    int* cdst     = (int*)alloc((size_t)EE * 4);
    int* cet      = (int*)alloc((size_t)EE * 4);

    const int EB = (EE + 255) / 256;        // 3125
    const int NB = (NN + 255) / 256;        // 196
    const int NHB = (NN * 4 + 255) / 256;   // 782
    const int MB128 = (NN + 127) / 128;     // 391

    // CSR build
    hipMemsetAsync(deg, 0, (size_t)NN * 4, stream);
    hist_kernel<<<EB, 256, 0, stream>>>(dst, deg, EE);
    block_sum_kernel<<<NB, 256, 0, stream>>>(deg, bsum, NN);
    scan_bsum_kernel<<<1, 256, 0, stream>>>(bsum, NB);
    scan_out_kernel<<<NB, 256, 0, stream>>>(deg, bsum, rowstart, cursor, NN);
    scatter_kernel<<<EB, 256, 0, stream>>>(src, dst, et, cursor, csrc, cdst, cet, EE);

    // es tables + weight packs/converts
    es_table_kernel<<<32, 64, 0, stream>>>(etab0, We0, ae0, es + 0, 4);
    es_table_kernel<<<32, 64, 0, stream>>>(etab1, We1, ae1, es + 32, 4);
    es_table_kernel<<<8, 64, 0, stream>>>(etab2, We2, ae2, es + 64, 1);
    pack_w2h<<<32, 256, 0, stream>>>(Wg2, resW2, wpkh);
    {
        int n0c = N0 * 128, n1c = N1 * 64, n2c = N2 * 32;
        int total = n0c + n1c + n2c + 8192 + 4096 + 2048 + 16384 + 65536;
        f2h8<<<(total + 255) / 256, 256, 0, stream>>>(
            x0, x0h, n0c, x1, x1h, n1c, x2, x2h, n2c,
            W0, W0h, 8192, W1, W1h, 4096, W2, W2h, 2048,
            Wg0, Wg0h, 16384, Wg1, Wg1h, 65536);
    }

    // input projections -> h0h [N,64] fp16
    gemm_mfma<4><<<dim3((N0 + 127) / 128, 1), 256, 0, stream>>>(x0h, W0h, b0, nullptr, h0h, N0, 64, 128);
    gemm_mfma<4><<<dim3((N1 + 127) / 128, 1), 256, 0, stream>>>(x1h, W1h, b1, nullptr, h0h + (size_t)N0 * 64, N1, 64, 64);
    gemm_mfma<4><<<dim3((N2 + 127) / 128, 1), 256, 0, stream>>>(x2h, W2h, b2, nullptr, h0h + (size_t)(N0 + N1) * 64, N2, 64, 32);

    // ---- GAT layer 0 ----
    gemm_mfma<8><<<dim3(MB128, 2), 256, 0, stream>>>(h0h, Wg0h, nullptr, nullptr, feath, NN, 256, 64);
    node_elr_h<<<NHB, 256, 0, stream>>>(feath, al0, ar0, el, er, NN);
    edge_logits_h4<<<EB, 256, 0, stream>>>(csrc, cdst, cet, el, er, es + 0, lg, EE);
    edge_softmax4<<<NB, 256, 0, stream>>>(rowstart, lg, (const float*)nullptr, a0, NN);
    aggregate256<<<(NN + 3) / 4, 256, 0, stream>>>(rowstart, csrc, a0, feath,
                                                   (const float*)nullptr, bufA, bufAh, NN);

    // ---- GAT layer 1 ----
    gemm_mfma<8><<<dim3(MB128, 2), 256, 0, stream>>>(bufAh, Wg1h, nullptr, nullptr, feath, NN, 256, 256);
    node_elr_h<<<NHB, 256, 0, stream>>>(feath, al1, ar1, el, er, NN);
    edge_logits_h4<<<EB, 256, 0, stream>>>(csrc, cdst, cet, el, er, es + 32, lg, EE);
    edge_softmax4<<<NB, 256, 0, stream>>>(rowstart, lg, a0, lg, NN);
    aggregate256<<<(NN + 3) / 4, 256, 0, stream>>>(rowstart, csrc, lg, feath,
                                                   bufA, (float*)nullptr, bufBh, NN);

    // ---- GAT layer 2 (H=1, C=16, linear residual, no act) ----
    gemm_mfma<2><<<dim3(MB128, 1), 256, 0, stream>>>(bufBh, wpkh, nullptr, cpack, nullptr, NN, 32, 256);
    node_elr_f2<<<NB, 256, 0, stream>>>(cpack, al2, ar2, el, er, NN);
    edge_logits_h1<<<EB, 256, 0, stream>>>(csrc, cdst, cet, el, er, es + 64, lg, EE);
    edge_softmax1<<<NB, 256, 0, stream>>>(rowstart, lg, NN);
    aggregate16<<<NHB, 256, 0, stream>>>(rowstart, csrc, lg, cpack, outp, NN);
}

// Round 4
// 570.034 us; speedup vs baseline: 2.2099x; 1.2103x over previous
//
#include <hip/hip_runtime.h>
#include <math.h>

#define N0 20000
#define N1 15000
#define N2 15000
#define NN 50000          // total nodes
#define EE 800000         // edges
#define SLOPE 0.2f
#define ALPHA 0.05f

typedef _Float16 h8 __attribute__((ext_vector_type(8)));
typedef _Float16 h4 __attribute__((ext_vector_type(4)));
typedef float f4v __attribute__((ext_vector_type(4)));

__device__ __forceinline__ float sel4(float4 v, int h) {
    float lo = (h & 1) ? v.y : v.x;
    float hi = (h & 1) ? v.w : v.z;
    return (h & 2) ? hi : lo;
}

// ---------------- CSR build ----------------

__global__ void hist_kernel(const int* __restrict__ dst, int* __restrict__ deg, int E_) {
    int e = blockIdx.x * blockDim.x + threadIdx.x;
    if (e < E_) atomicAdd(&deg[dst[e]], 1);
}

__global__ __launch_bounds__(256) void block_sum_kernel(const int* __restrict__ deg,
                                                        int* __restrict__ bsum, int n) {
    int i = blockIdx.x * 256 + threadIdx.x;
    int v = (i < n) ? deg[i] : 0;
    #pragma unroll
    for (int off = 32; off > 0; off >>= 1) v += __shfl_down(v, off);
    __shared__ int sh[4];
    if ((threadIdx.x & 63) == 0) sh[threadIdx.x >> 6] = v;
    __syncthreads();
    if (threadIdx.x == 0) bsum[blockIdx.x] = sh[0] + sh[1] + sh[2] + sh[3];
}

__global__ __launch_bounds__(256) void scan_bsum_kernel(int* __restrict__ bsum, int nb) {
    __shared__ int sh[256];
    int tid = threadIdx.x;
    int v = (tid < nb) ? bsum[tid] : 0;
    sh[tid] = v;
    __syncthreads();
    #pragma unroll
    for (int off = 1; off < 256; off <<= 1) {
        int t = (tid >= off) ? sh[tid - off] : 0;
        __syncthreads();
        sh[tid] += t;
        __syncthreads();
    }
    if (tid < nb) bsum[tid] = sh[tid] - v;   // exclusive
}

__global__ __launch_bounds__(256) void scan_out_kernel(const int* __restrict__ deg,
                                                       const int* __restrict__ boff,
                                                       int* __restrict__ rowstart,
                                                       int* __restrict__ cursor, int n) {
    __shared__ int sh[256];
    int tid = threadIdx.x;
    int i = blockIdx.x * 256 + tid;
    int v = (i < n) ? deg[i] : 0;
    sh[tid] = v;
    __syncthreads();
    #pragma unroll
    for (int off = 1; off < 256; off <<= 1) {
        int t = (tid >= off) ? sh[tid - off] : 0;
        __syncthreads();
        sh[tid] += t;
        __syncthreads();
    }
    int excl = sh[tid] - v + boff[blockIdx.x];
    if (i < n) { rowstart[i] = excl; cursor[i] = excl; }
    if (i == n - 1) rowstart[n] = excl + v;
}

// pack (et<<16)|src into one int per CSR slot
__global__ void scatter_kernel(const int* __restrict__ src, const int* __restrict__ dst,
                               const int* __restrict__ et, int* __restrict__ cursor,
                               int* __restrict__ pk, int E_) {
    int e = blockIdx.x * blockDim.x + threadIdx.x;
    if (e >= E_) return;
    int d = dst[e];
    int p = atomicAdd(&cursor[d], 1);
    pk[p] = (et[e] << 16) | src[e];
}

// ---------------- es table ----------------

__global__ void es_table_kernel(const float* __restrict__ etab, const float* __restrict__ We,
                                const float* __restrict__ ae, float* __restrict__ es, int H) {
    int b = blockIdx.x;
    int t = b / H, h = b % H;
    int j = threadIdx.x;   // 0..63
    const float* w = We + (size_t)(h * 64 + j) * 64;
    const float* e = etab + t * 64;
    float s = 0.f;
    #pragma unroll
    for (int k = 0; k < 64; k += 4) {
        float4 wv = *(const float4*)(w + k);
        float4 ev = *(const float4*)(e + k);
        s += wv.x * ev.x + wv.y * ev.y + wv.z * ev.z + wv.w * ev.w;
    }
    s *= ae[h * 64 + j];
    #pragma unroll
    for (int off = 32; off > 0; off >>= 1) s += __shfl_down(s, off);
    if (j == 0) es[t * H + h] = s;
}

// ---------------- weight pack for layer 2 (fp16) ----------------

__global__ void pack_w2h(const float* __restrict__ Wg, const float* __restrict__ Wr,
                         _Float16* __restrict__ out) {
    int t = blockIdx.x * 256 + threadIdx.x;
    if (t < 8192) out[t] = (_Float16)((t < 4096) ? Wg[t] : Wr[t - 4096]);
}

// ---------------- fp32 -> fp16 converts (8 arrays, one launch) ----------------

__global__ void f2h8(const float* s0, _Float16* d0, int n0,
                     const float* s1, _Float16* d1, int n1,
                     const float* s2, _Float16* d2, int n2,
                     const float* s3, _Float16* d3, int n3,
                     const float* s4, _Float16* d4, int n4,
                     const float* s5, _Float16* d5, int n5,
                     const float* s6, _Float16* d6, int n6,
                     const float* s7, _Float16* d7, int n7) {
    int t = blockIdx.x * 256 + threadIdx.x;
    if (t < n0) { d0[t] = (_Float16)s0[t]; return; } t -= n0;
    if (t < n1) { d1[t] = (_Float16)s1[t]; return; } t -= n1;
    if (t < n2) { d2[t] = (_Float16)s2[t]; return; } t -= n2;
    if (t < n3) { d3[t] = (_Float16)s3[t]; return; } t -= n3;
    if (t < n4) { d4[t] = (_Float16)s4[t]; return; } t -= n4;
    if (t < n5) { d5[t] = (_Float16)s5[t]; return; } t -= n5;
    if (t < n6) { d6[t] = (_Float16)s6[t]; return; } t -= n6;
    if (t < n7) { d7[t] = (_Float16)s7[t]; }
}

// ---------------- MFMA fp16 GEMM (unchanged, verified) ----------------

template<int NT>
__global__ __launch_bounds__(256) void gemm_mfma(const _Float16* __restrict__ A,
                                                 const _Float16* __restrict__ B,
                                                 const float* __restrict__ bias,
                                                 float* __restrict__ Cf,
                                                 _Float16* __restrict__ Ch,
                                                 int M, int N, int K) {
    const int wave = threadIdx.x >> 6;
    const int lane = threadIdx.x & 63;
    const int m_base = (blockIdx.x * 4 + wave) * 32;
    const int n_base = blockIdx.y * (NT * 16);
    const int row = lane & 15;
    const int kq = (lane >> 4) * 8;

    f4v acc[2][NT];
    #pragma unroll
    for (int i = 0; i < 2; i++)
        #pragma unroll
        for (int j = 0; j < NT; j++) {
            f4v z = {0.f, 0.f, 0.f, 0.f};
            acc[i][j] = z;
        }

    int r0 = m_base + row;      if (r0 >= M) r0 = M - 1;
    int r1 = m_base + 16 + row; if (r1 >= M) r1 = M - 1;
    const _Float16* a0p = A + (size_t)r0 * K + kq;
    const _Float16* a1p = A + (size_t)r1 * K + kq;
    const _Float16* bp  = B + (size_t)(n_base + row) * K + kq;

    for (int k = 0; k < K; k += 32) {
        h8 a0 = *(const h8*)(a0p + k);
        h8 a1 = *(const h8*)(a1p + k);
        #pragma unroll
        for (int j = 0; j < NT; j++) {
            h8 b = *(const h8*)(bp + (size_t)j * 16 * K + k);
            acc[0][j] = __builtin_amdgcn_mfma_f32_16x16x32_f16(a0, b, acc[0][j], 0, 0, 0);
            acc[1][j] = __builtin_amdgcn_mfma_f32_16x16x32_f16(a1, b, acc[1][j], 0, 0, 0);
        }
    }

    const int col = lane & 15;
    const int rb = (lane >> 4) * 4;
    #pragma unroll
    for (int ms = 0; ms < 2; ms++) {
        #pragma unroll
        for (int j = 0; j < NT; j++) {
            #pragma unroll
            for (int r = 0; r < 4; r++) {
                int m = m_base + ms * 16 + rb + r;
                if (m < M) {
                    int n = n_base + j * 16 + col;
                    float v = acc[ms][j][r];
                    if (bias) v += bias[n];
                    if (Cf) Cf[(size_t)m * N + n] = v;
                    if (Ch) Ch[(size_t)m * N + n] = (_Float16)v;
                }
            }
        }
    }
}

// ---------------- per-node el/er ----------------

__global__ void node_elr_h(const _Float16* __restrict__ feat, const float* __restrict__ al,
                           const float* __restrict__ ar, float* __restrict__ el,
                           float* __restrict__ er, int nN) {
    int t = blockIdx.x * blockDim.x + threadIdx.x;
    if (t >= nN * 4) return;
    int n = t >> 2, h = t & 3;
    const _Float16* f = feat + (size_t)n * 256 + h * 64;
    const float* a = al + h * 64;
    const float* r = ar + h * 64;
    float sl = 0.f, sr = 0.f;
    #pragma unroll
    for (int j = 0; j < 64; j += 8) {
        h8 fv = *(const h8*)(f + j);
        #pragma unroll
        for (int q = 0; q < 8; q++) {
            float x = (float)fv[q];
            sl = fmaf(x, a[j + q], sl);
            sr = fmaf(x, r[j + q], sr);
        }
    }
    el[t] = sl; er[t] = sr;
}

__global__ void node_elr_f2(const float* __restrict__ feat, const float* __restrict__ al,
                            const float* __restrict__ ar, float* __restrict__ el,
                            float* __restrict__ er, int nN) {
    int t = blockIdx.x * blockDim.x + threadIdx.x;
    if (t >= nN) return;
    const float* f = feat + (size_t)t * 32;
    float sl = 0.f, sr = 0.f;
    #pragma unroll
    for (int j = 0; j < 16; j += 4) {
        float4 fv = *(const float4*)(f + j);
        float4 av = *(const float4*)(al + j);
        float4 rv = *(const float4*)(ar + j);
        sl += fv.x * av.x + fv.y * av.y + fv.z * av.z + fv.w * av.w;
        sr += fv.x * rv.x + fv.y * rv.y + fv.z * rv.z + fv.w * rv.w;
    }
    el[t] = sl; er[t] = sr;
}

// ---------------- fused GAT edge stage, H=4: logits+softmax+blend+aggregate+res+ELU ----------------
// one wave per dst node; LDS caches attention for first 64 edges (deg>64 ~impossible
// for Poisson(16) but handled by inline recompute).

template<bool WRITE_A, bool HAS_PREV, bool HAS_RES>
__global__ __launch_bounds__(256) void gat_fused4(const int* __restrict__ rowstart,
                                                  const int* __restrict__ pk,
                                                  const float* __restrict__ el,
                                                  const float* __restrict__ er,
                                                  const float* __restrict__ es,
                                                  const _Float16* __restrict__ feat,
                                                  const float* __restrict__ aprev,
                                                  float* __restrict__ awrite,
                                                  const float* __restrict__ res,
                                                  float* __restrict__ outf,
                                                  _Float16* __restrict__ outh, int nN) {
    __shared__ float a_lds[4][64 * 4];
    const int wave = threadIdx.x >> 6;
    const int lane = threadIdx.x & 63;
    int n = blockIdx.x * 4 + wave;
    if (n >= nN) return;
    const int r0 = rowstart[n], r1 = rowstart[n + 1];
    float4 er4 = *(const float4*)(er + n * 4);

    // phase 1: per-head max over edges (lanes parallel)
    float4 m4 = {-INFINITY, -INFINITY, -INFINITY, -INFINITY};
    for (int base = r0; base < r1; base += 64) {
        int idx = base + lane;
        if (idx < r1) {
            int p = pk[idx];
            float4 e4 = *(const float4*)(el + (p & 0xFFFF) * 4);
            float4 c4 = *(const float4*)(es + (p >> 16) * 4);
            float v;
            v = e4.x + er4.x + c4.x; v = v > 0.f ? v : SLOPE * v; m4.x = fmaxf(m4.x, v);
            v = e4.y + er4.y + c4.y; v = v > 0.f ? v : SLOPE * v; m4.y = fmaxf(m4.y, v);
            v = e4.z + er4.z + c4.z; v = v > 0.f ? v : SLOPE * v; m4.z = fmaxf(m4.z, v);
            v = e4.w + er4.w + c4.w; v = v > 0.f ? v : SLOPE * v; m4.w = fmaxf(m4.w, v);
        }
    }
    #pragma unroll
    for (int off = 1; off < 64; off <<= 1) {
        m4.x = fmaxf(m4.x, __shfl_xor(m4.x, off));
        m4.y = fmaxf(m4.y, __shfl_xor(m4.y, off));
        m4.z = fmaxf(m4.z, __shfl_xor(m4.z, off));
        m4.w = fmaxf(m4.w, __shfl_xor(m4.w, off));
    }

    // phase 2: exp + sum; cache first 64 exps in LDS
    float4 s4 = {0.f, 0.f, 0.f, 0.f};
    for (int base = r0; base < r1; base += 64) {
        int idx = base + lane;
        if (idx < r1) {
            int p = pk[idx];
            float4 e4 = *(const float4*)(el + (p & 0xFFFF) * 4);
            float4 c4 = *(const float4*)(es + (p >> 16) * 4);
            float4 ex;
            float v;
            v = e4.x + er4.x + c4.x; v = v > 0.f ? v : SLOPE * v; ex.x = __expf(v - m4.x);
            v = e4.y + er4.y + c4.y; v = v > 0.f ? v : SLOPE * v; ex.y = __expf(v - m4.y);
            v = e4.z + er4.z + c4.z; v = v > 0.f ? v : SLOPE * v; ex.z = __expf(v - m4.z);
            v = e4.w + er4.w + c4.w; v = v > 0.f ? v : SLOPE * v; ex.w = __expf(v - m4.w);
            if (base == r0) *(float4*)&a_lds[wave][lane * 4] = ex;
            s4.x += ex.x; s4.y += ex.y; s4.z += ex.z; s4.w += ex.w;
        }
    }
    #pragma unroll
    for (int off = 1; off < 64; off <<= 1) {
        s4.x += __shfl_xor(s4.x, off);
        s4.y += __shfl_xor(s4.y, off);
        s4.z += __shfl_xor(s4.z, off);
        s4.w += __shfl_xor(s4.w, off);
    }
    float4 inv;
    inv.x = 1.f / (s4.x + 1e-9f); inv.y = 1.f / (s4.y + 1e-9f);
    inv.z = 1.f / (s4.z + 1e-9f); inv.w = 1.f / (s4.w + 1e-9f);

    // phase 2b: finalize first-64 attention in LDS (+ optional blend / a-write)
    {
        int idx = r0 + lane;
        if (idx < r1) {
            float4 a = *(const float4*)&a_lds[wave][lane * 4];
            a.x *= inv.x; a.y *= inv.y; a.z *= inv.z; a.w *= inv.w;
            if (HAS_PREV) {
                float4 pv = *(const float4*)(aprev + (size_t)idx * 4);
                a.x = a.x * (1.f - ALPHA) + ALPHA * pv.x;
                a.y = a.y * (1.f - ALPHA) + ALPHA * pv.y;
                a.z = a.z * (1.f - ALPHA) + ALPHA * pv.z;
                a.w = a.w * (1.f - ALPHA) + ALPHA * pv.w;
            }
            if (WRITE_A) *(float4*)(awrite + (size_t)idx * 4) = a;
            *(float4*)&a_lds[wave][lane * 4] = a;
        }
    }
    if (WRITE_A) {   // rare tail (deg > 64)
        for (int base = r0 + 64; base < r1; base += 64) {
            int idx = base + lane;
            if (idx < r1) {
                int p = pk[idx];
                float4 e4 = *(const float4*)(el + (p & 0xFFFF) * 4);
                float4 c4 = *(const float4*)(es + (p >> 16) * 4);
                float4 a;
                float v;
                v = e4.x + er4.x + c4.x; v = v > 0.f ? v : SLOPE * v; a.x = __expf(v - m4.x) * inv.x;
                v = e4.y + er4.y + c4.y; v = v > 0.f ? v : SLOPE * v; a.y = __expf(v - m4.y) * inv.y;
                v = e4.z + er4.z + c4.z; v = v > 0.f ? v : SLOPE * v; a.z = __expf(v - m4.z) * inv.z;
                v = e4.w + er4.w + c4.w; v = v > 0.f ? v : SLOPE * v; a.w = __expf(v - m4.w) * inv.w;
                *(float4*)(awrite + (size_t)idx * 4) = a;
            }
        }
    }

    // phase 3: aggregate (lanes = feature columns), unroll 2
    const int h = lane >> 4;
    float4 acc = {0.f, 0.f, 0.f, 0.f};
    const int cap = min(r1, r0 + 64);
    int i = r0;
    for (; i + 1 < cap; i += 2) {
        int p0 = pk[i], p1 = pk[i + 1];
        float a0v = a_lds[wave][(i - r0) * 4 + h];
        float a1v = a_lds[wave][(i + 1 - r0) * 4 + h];
        h4 f0 = *(const h4*)(feat + (size_t)(p0 & 0xFFFF) * 256 + lane * 4);
        h4 f1 = *(const h4*)(feat + (size_t)(p1 & 0xFFFF) * 256 + lane * 4);
        acc.x = fmaf(a0v, (float)f0[0], acc.x);
        acc.y = fmaf(a0v, (float)f0[1], acc.y);
        acc.z = fmaf(a0v, (float)f0[2], acc.z);
        acc.w = fmaf(a0v, (float)f0[3], acc.w);
        acc.x = fmaf(a1v, (float)f1[0], acc.x);
        acc.y = fmaf(a1v, (float)f1[1], acc.y);
        acc.z = fmaf(a1v, (float)f1[2], acc.z);
        acc.w = fmaf(a1v, (float)f1[3], acc.w);
    }
    if (i < cap) {
        int p0 = pk[i];
        float a0v = a_lds[wave][(i - r0) * 4 + h];
        h4 f0 = *(const h4*)(feat + (size_t)(p0 & 0xFFFF) * 256 + lane * 4);
        acc.x = fmaf(a0v, (float)f0[0], acc.x);
        acc.y = fmaf(a0v, (float)f0[1], acc.y);
        acc.z = fmaf(a0v, (float)f0[2], acc.z);
        acc.w = fmaf(a0v, (float)f0[3], acc.w);
        i++;
    }
    if (i < r1) {  // deg > 64 tail: recompute attention inline
        float mh = sel4(m4, h), invh = sel4(inv, h), erh = sel4(er4, h);
        for (; i < r1; i++) {
            int p = pk[i];
            int s = p & 0xFFFF, t = p >> 16;
            float v = el[s * 4 + h] + erh + es[t * 4 + h];
            v = v > 0.f ? v : SLOPE * v;
            float a = __expf(v - mh) * invh;
            if (HAS_PREV) a = a * (1.f - ALPHA) + ALPHA * aprev[(size_t)i * 4 + h];
            h4 f = *(const h4*)(feat + (size_t)s * 256 + lane * 4);
            acc.x = fmaf(a, (float)f[0], acc.x);
            acc.y = fmaf(a, (float)f[1], acc.y);
            acc.z = fmaf(a, (float)f[2], acc.z);
            acc.w = fmaf(a, (float)f[3], acc.w);
        }
    }

    if (HAS_RES) {
        float4 r = *(const float4*)(res + (size_t)n * 256 + lane * 4);
        acc.x += r.x; acc.y += r.y; acc.z += r.z; acc.w += r.w;
    }
    acc.x = acc.x > 0.f ? acc.x : expm1f(acc.x);
    acc.y = acc.y > 0.f ? acc.y : expm1f(acc.y);
    acc.z = acc.z > 0.f ? acc.z : expm1f(acc.z);
    acc.w = acc.w > 0.f ? acc.w : expm1f(acc.w);
    if (outf) *(float4*)(outf + (size_t)n * 256 + lane * 4) = acc;
    if (outh) {
        h4 o;
        o[0] = (_Float16)acc.x; o[1] = (_Float16)acc.y;
        o[2] = (_Float16)acc.z; o[3] = (_Float16)acc.w;
        *(h4*)(outh + (size_t)n * 256 + lane * 4) = o;
    }
}

// ---------------- fused GAT layer 2 (H=1, C=16): 16-lane groups, writes d_out ----------------

__global__ __launch_bounds__(256) void gat_fused1(const int* __restrict__ rowstart,
                                                  const int* __restrict__ pk,
                                                  const float* __restrict__ el,
                                                  const float* __restrict__ er,
                                                  const float* __restrict__ es,
                                                  const float* __restrict__ cpack,
                                                  float* __restrict__ out, int nN) {
    __shared__ float a_lds[16][64];
    const int wave = threadIdx.x >> 6;
    const int lane = threadIdx.x & 63;
    const int g = lane >> 4, li = lane & 15;
    const int gi = wave * 4 + g;
    int n = blockIdx.x * 16 + gi;
    if (n >= nN) return;
    const int r0 = rowstart[n], r1 = rowstart[n + 1];
    const float ern = er[n];

    float m = -INFINITY;
    for (int base = r0; base < r1; base += 16) {
        int idx = base + li;
        if (idx < r1) {
            int p = pk[idx];
            float v = el[p & 0xFFFF] + ern + es[p >> 16];
            v = v > 0.f ? v : SLOPE * v;
            m = fmaxf(m, v);
        }
    }
    #pragma unroll
    for (int off = 1; off < 16; off <<= 1) m = fmaxf(m, __shfl_xor(m, off, 16));

    float s = 0.f;
    for (int base = r0; base < r1; base += 16) {
        int idx = base + li;
        if (idx < r1) {
            int p = pk[idx];
            float v = el[p & 0xFFFF] + ern + es[p >> 16];
            v = v > 0.f ? v : SLOPE * v;
            float e = __expf(v - m);
            if (idx - r0 < 64) a_lds[gi][idx - r0] = e;
            s += e;
        }
    }
    #pragma unroll
    for (int off = 1; off < 16; off <<= 1) s += __shfl_xor(s, off, 16);
    float inv = 1.f / (s + 1e-9f);

    int capn = min(r1 - r0, 64);
    for (int o = li; o < capn; o += 16) a_lds[gi][o] *= inv;

    float acc = 0.f;
    const int cap = r0 + capn;
    int i = r0;
    for (; i + 1 < cap; i += 2) {
        int p0 = pk[i], p1 = pk[i + 1];
        float a0v = a_lds[gi][i - r0];
        float a1v = a_lds[gi][i + 1 - r0];
        float f0 = cpack[(size_t)(p0 & 0xFFFF) * 32 + li];
        float f1 = cpack[(size_t)(p1 & 0xFFFF) * 32 + li];
        acc = fmaf(a0v, f0, acc);
        acc = fmaf(a1v, f1, acc);
    }
    if (i < cap) {
        acc = fmaf(a_lds[gi][i - r0], cpack[(size_t)(pk[i] & 0xFFFF) * 32 + li], acc);
        i++;
    }
    for (; i < r1; i++) {   // deg > 64 tail
        int p = pk[i];
        float v = el[p & 0xFFFF] + ern + es[p >> 16];
        v = v > 0.f ? v : SLOPE * v;
        float a = __expf(v - m) * inv;
        acc = fmaf(a, cpack[(size_t)(p & 0xFFFF) * 32 + li], acc);
    }
    out[(size_t)n * 16 + li] = acc + cpack[(size_t)n * 32 + 16 + li];
}

// ---------------- host ----------------

extern "C" void kernel_launch(void* const* d_in, const int* in_sizes, int n_in,
                              void* d_out, int out_size, void* d_ws, size_t ws_size,
                              hipStream_t stream) {
    const float* x0 = (const float*)d_in[0];
    const float* x1 = (const float*)d_in[1];
    const float* x2 = (const float*)d_in[2];
    const int* src  = (const int*)d_in[3];
    const int* dst  = (const int*)d_in[4];
    const int* et   = (const int*)d_in[5];
    const float* W0 = (const float*)d_in[6];  const float* b0 = (const float*)d_in[7];
    const float* W1 = (const float*)d_in[8];  const float* b1 = (const float*)d_in[9];
    const float* W2 = (const float*)d_in[10]; const float* b2 = (const float*)d_in[11];
    const float* Wg0 = (const float*)d_in[12]; const float* etab0 = (const float*)d_in[13];
    const float* We0 = (const float*)d_in[14]; const float* al0 = (const float*)d_in[15];
    const float* ar0 = (const float*)d_in[16]; const float* ae0 = (const float*)d_in[17];
    const float* Wg1 = (const float*)d_in[18]; const float* etab1 = (const float*)d_in[19];
    const float* We1 = (const float*)d_in[20]; const float* al1 = (const float*)d_in[21];
    const float* ar1 = (const float*)d_in[22]; const float* ae1 = (const float*)d_in[23];
    const float* Wg2 = (const float*)d_in[24]; const float* etab2 = (const float*)d_in[25];
    const float* We2 = (const float*)d_in[26]; const float* al2 = (const float*)d_in[27];
    const float* ar2 = (const float*)d_in[28]; const float* ae2 = (const float*)d_in[29];
    const float* resW2 = (const float*)d_in[30];
    float* outp = (float*)d_out;

    char* p = (char*)d_ws;
    auto alloc = [&](size_t bytes) -> void* {
        void* r = (void*)p;
        p += (bytes + 255) & ~(size_t)255;
        return r;
    };
    _Float16* x0h   = (_Float16*)alloc((size_t)N0 * 128 * 2);
    _Float16* x1h   = (_Float16*)alloc((size_t)N1 * 64 * 2);
    _Float16* x2h   = (_Float16*)alloc((size_t)N2 * 32 * 2);
    _Float16* W0h   = (_Float16*)alloc(64 * 128 * 2);
    _Float16* W1h   = (_Float16*)alloc(64 * 64 * 2);
    _Float16* W2h   = (_Float16*)alloc(64 * 32 * 2);
    _Float16* Wg0h  = (_Float16*)alloc(256 * 64 * 2);
    _Float16* Wg1h  = (_Float16*)alloc(256 * 256 * 2);
    _Float16* wpkh  = (_Float16*)alloc(32 * 256 * 2);
    _Float16* h0h   = (_Float16*)alloc((size_t)NN * 64 * 2);
    _Float16* feath = (_Float16*)alloc((size_t)NN * 256 * 2);
    _Float16* bufAh = (_Float16*)alloc((size_t)NN * 256 * 2);
    _Float16* bufBh = (_Float16*)alloc((size_t)NN * 256 * 2);
    float* bufA  = (float*)alloc((size_t)NN * 256 * 4);
    float* el    = (float*)alloc((size_t)NN * 4 * 4);
    float* er    = (float*)alloc((size_t)NN * 4 * 4);
    float* a0    = (float*)alloc((size_t)EE * 4 * 4);
    float* es    = (float*)alloc(96 * 4);
    float* cpack = (float*)alloc((size_t)NN * 32 * 4);
    int* rowstart = (int*)alloc((size_t)(NN + 1) * 4);
    int* deg      = (int*)alloc((size_t)NN * 4);
    int* cursor   = (int*)alloc((size_t)NN * 4);
    int* bsum     = (int*)alloc(256 * 4);
    int* pk       = (int*)alloc((size_t)EE * 4);

    const int EB = (EE + 255) / 256;        // 3125
    const int NB = (NN + 255) / 256;        // 196
    const int NHB = (NN * 4 + 255) / 256;   // 782
    const int MB128 = (NN + 127) / 128;     // 391

    // CSR build
    hipMemsetAsync(deg, 0, (size_t)NN * 4, stream);
    hist_kernel<<<EB, 256, 0, stream>>>(dst, deg, EE);
    block_sum_kernel<<<NB, 256, 0, stream>>>(deg, bsum, NN);
    scan_bsum_kernel<<<1, 256, 0, stream>>>(bsum, NB);
    scan_out_kernel<<<NB, 256, 0, stream>>>(deg, bsum, rowstart, cursor, NN);
    scatter_kernel<<<EB, 256, 0, stream>>>(src, dst, et, cursor, pk, EE);

    // es tables + weight packs/converts
    es_table_kernel<<<32, 64, 0, stream>>>(etab0, We0, ae0, es + 0, 4);
    es_table_kernel<<<32, 64, 0, stream>>>(etab1, We1, ae1, es + 32, 4);
    es_table_kernel<<<8, 64, 0, stream>>>(etab2, We2, ae2, es + 64, 1);
    pack_w2h<<<32, 256, 0, stream>>>(Wg2, resW2, wpkh);
    {
        int n0c = N0 * 128, n1c = N1 * 64, n2c = N2 * 32;
        int total = n0c + n1c + n2c + 8192 + 4096 + 2048 + 16384 + 65536;
        f2h8<<<(total + 255) / 256, 256, 0, stream>>>(
            x0, x0h, n0c, x1, x1h, n1c, x2, x2h, n2c,
            W0, W0h, 8192, W1, W1h, 4096, W2, W2h, 2048,
            Wg0, Wg0h, 16384, Wg1, Wg1h, 65536);
    }

    // input projections -> h0h [N,64] fp16
    gemm_mfma<4><<<dim3((N0 + 127) / 128, 1), 256, 0, stream>>>(x0h, W0h, b0, nullptr, h0h, N0, 64, 128);
    gemm_mfma<4><<<dim3((N1 + 127) / 128, 1), 256, 0, stream>>>(x1h, W1h, b1, nullptr, h0h + (size_t)N0 * 64, N1, 64, 64);
    gemm_mfma<4><<<dim3((N2 + 127) / 128, 1), 256, 0, stream>>>(x2h, W2h, b2, nullptr, h0h + (size_t)(N0 + N1) * 64, N2, 64, 32);

    // ---- GAT layer 0 ----
    gemm_mfma<8><<<dim3(MB128, 2), 256, 0, stream>>>(h0h, Wg0h, nullptr, nullptr, feath, NN, 256, 64);
    node_elr_h<<<NHB, 256, 0, stream>>>(feath, al0, ar0, el, er, NN);
    gat_fused4<true, false, false><<<(NN + 3) / 4, 256, 0, stream>>>(
        rowstart, pk, el, er, es + 0, feath, nullptr, a0, nullptr, bufA, bufAh, NN);

    // ---- GAT layer 1 ----
    gemm_mfma<8><<<dim3(MB128, 2), 256, 0, stream>>>(bufAh, Wg1h, nullptr, nullptr, feath, NN, 256, 256);
    node_elr_h<<<NHB, 256, 0, stream>>>(feath, al1, ar1, el, er, NN);
    gat_fused4<false, true, true><<<(NN + 3) / 4, 256, 0, stream>>>(
        rowstart, pk, el, er, es + 32, feath, a0, nullptr, bufA, nullptr, bufBh, NN);

    // ---- GAT layer 2 (H=1, C=16, linear residual, no act) ----
    gemm_mfma<2><<<dim3(MB128, 1), 256, 0, stream>>>(bufBh, wpkh, nullptr, cpack, nullptr, NN, 32, 256);
    node_elr_f2<<<NB, 256, 0, stream>>>(cpack, al2, ar2, el, er, NN);
    gat_fused1<<<(NN + 15) / 16, 256, 0, stream>>>(rowstart, pk, el, er, es + 64, cpack, outp, NN);
}

// Round 6
// 536.869 us; speedup vs baseline: 2.3464x; 1.0618x over previous
//
#include <hip/hip_runtime.h>
#include <math.h>

#define N0 20000
#define N1 15000
#define N2 15000
#define NN 50000          // total nodes
#define EE 800000         // edges
#define SLOPE 0.2f
#define ALPHA 0.05f

typedef _Float16 h8 __attribute__((ext_vector_type(8)));
typedef _Float16 h4 __attribute__((ext_vector_type(4)));
typedef float f4v __attribute__((ext_vector_type(4)));

__device__ __forceinline__ float sel4(float4 v, int h) {
    float lo = (h & 1) ? v.y : v.x;
    float hi = (h & 1) ? v.w : v.z;
    return (h & 2) ? hi : lo;
}

// ---------------- CSR build ----------------

__global__ void hist_kernel(const int* __restrict__ dst, int* __restrict__ deg, int E_) {
    int e = blockIdx.x * blockDim.x + threadIdx.x;
    if (e < E_) atomicAdd(&deg[dst[e]], 1);
}

__global__ __launch_bounds__(256) void block_sum_kernel(const int* __restrict__ deg,
                                                        int* __restrict__ bsum, int n) {
    int i = blockIdx.x * 256 + threadIdx.x;
    int v = (i < n) ? deg[i] : 0;
    #pragma unroll
    for (int off = 32; off > 0; off >>= 1) v += __shfl_down(v, off);
    __shared__ int sh[4];
    if ((threadIdx.x & 63) == 0) sh[threadIdx.x >> 6] = v;
    __syncthreads();
    if (threadIdx.x == 0) bsum[blockIdx.x] = sh[0] + sh[1] + sh[2] + sh[3];
}

__global__ __launch_bounds__(256) void scan_bsum_kernel(int* __restrict__ bsum, int nb) {
    __shared__ int sh[256];
    int tid = threadIdx.x;
    int v = (tid < nb) ? bsum[tid] : 0;
    sh[tid] = v;
    __syncthreads();
    #pragma unroll
    for (int off = 1; off < 256; off <<= 1) {
        int t = (tid >= off) ? sh[tid - off] : 0;
        __syncthreads();
        sh[tid] += t;
        __syncthreads();
    }
    if (tid < nb) bsum[tid] = sh[tid] - v;   // exclusive
}

__global__ __launch_bounds__(256) void scan_out_kernel(const int* __restrict__ deg,
                                                       const int* __restrict__ boff,
                                                       int* __restrict__ rowstart,
                                                       int* __restrict__ cursor, int n) {
    __shared__ int sh[256];
    int tid = threadIdx.x;
    int i = blockIdx.x * 256 + tid;
    int v = (i < n) ? deg[i] : 0;
    sh[tid] = v;
    __syncthreads();
    #pragma unroll
    for (int off = 1; off < 256; off <<= 1) {
        int t = (tid >= off) ? sh[tid - off] : 0;
        __syncthreads();
        sh[tid] += t;
        __syncthreads();
    }
    int excl = sh[tid] - v + boff[blockIdx.x];
    if (i < n) { rowstart[i] = excl; cursor[i] = excl; }
    if (i == n - 1) rowstart[n] = excl + v;
}

// pack (et<<16)|src into one int per CSR slot
__global__ void scatter_kernel(const int* __restrict__ src, const int* __restrict__ dst,
                               const int* __restrict__ et, int* __restrict__ cursor,
                               int* __restrict__ pk, int E_) {
    int e = blockIdx.x * blockDim.x + threadIdx.x;
    if (e >= E_) return;
    int d = dst[e];
    int p = atomicAdd(&cursor[d], 1);
    pk[p] = (et[e] << 16) | src[e];
}

// ---------------- es tables (all 3 layers, one launch) ----------------

__global__ void es_table_all(const float* __restrict__ etab0, const float* __restrict__ We0,
                             const float* __restrict__ ae0,
                             const float* __restrict__ etab1, const float* __restrict__ We1,
                             const float* __restrict__ ae1,
                             const float* __restrict__ etab2, const float* __restrict__ We2,
                             const float* __restrict__ ae2,
                             float* __restrict__ es) {
    int b = blockIdx.x;
    const float *etab, *We, *ae;
    float* out;
    int H;
    if (b < 32)      { etab = etab0; We = We0; ae = ae0; out = es;      H = 4; }
    else if (b < 64) { b -= 32; etab = etab1; We = We1; ae = ae1; out = es + 32; H = 4; }
    else             { b -= 64; etab = etab2; We = We2; ae = ae2; out = es + 64; H = 1; }
    int t = b / H, h = b % H;
    int j = threadIdx.x;   // 0..63
    const float* w = We + (size_t)(h * 64 + j) * 64;
    const float* e = etab + t * 64;
    float s = 0.f;
    #pragma unroll
    for (int k = 0; k < 64; k += 4) {
        float4 wv = *(const float4*)(w + k);
        float4 ev = *(const float4*)(e + k);
        s += wv.x * ev.x + wv.y * ev.y + wv.z * ev.z + wv.w * ev.w;
    }
    s *= ae[h * 64 + j];
    #pragma unroll
    for (int off = 32; off > 0; off >>= 1) s += __shfl_down(s, off);
    if (j == 0) out[t * H + h] = s;
}

// ---------------- fp32 -> fp16 converts (10 arrays, one launch) ----------------

__global__ void f2h10(const float* s0, _Float16* d0, int n0,
                      const float* s1, _Float16* d1, int n1,
                      const float* s2, _Float16* d2, int n2,
                      const float* s3, _Float16* d3, int n3,
                      const float* s4, _Float16* d4, int n4,
                      const float* s5, _Float16* d5, int n5,
                      const float* s6, _Float16* d6, int n6,
                      const float* s7, _Float16* d7, int n7,
                      const float* s8, _Float16* d8, int n8,
                      const float* s9, _Float16* d9, int n9) {
    int t = blockIdx.x * 256 + threadIdx.x;
    if (t < n0) { d0[t] = (_Float16)s0[t]; return; } t -= n0;
    if (t < n1) { d1[t] = (_Float16)s1[t]; return; } t -= n1;
    if (t < n2) { d2[t] = (_Float16)s2[t]; return; } t -= n2;
    if (t < n3) { d3[t] = (_Float16)s3[t]; return; } t -= n3;
    if (t < n4) { d4[t] = (_Float16)s4[t]; return; } t -= n4;
    if (t < n5) { d5[t] = (_Float16)s5[t]; return; } t -= n5;
    if (t < n6) { d6[t] = (_Float16)s6[t]; return; } t -= n6;
    if (t < n7) { d7[t] = (_Float16)s7[t]; return; } t -= n7;
    if (t < n8) { d8[t] = (_Float16)s8[t]; return; } t -= n8;
    if (t < n9) { d9[t] = (_Float16)s9[t]; }
}

// ---------------- MFMA fp16 GEMM (verified) ----------------

template<int NT>
__global__ __launch_bounds__(256) void gemm_mfma(const _Float16* __restrict__ A,
                                                 const _Float16* __restrict__ B,
                                                 const float* __restrict__ bias,
                                                 float* __restrict__ Cf,
                                                 _Float16* __restrict__ Ch,
                                                 int M, int N, int K) {
    const int wave = threadIdx.x >> 6;
    const int lane = threadIdx.x & 63;
    const int m_base = (blockIdx.x * 4 + wave) * 32;
    const int n_base = blockIdx.y * (NT * 16);
    const int row = lane & 15;
    const int kq = (lane >> 4) * 8;

    f4v acc[2][NT];
    #pragma unroll
    for (int i = 0; i < 2; i++)
        #pragma unroll
        for (int j = 0; j < NT; j++) {
            f4v z = {0.f, 0.f, 0.f, 0.f};
            acc[i][j] = z;
        }

    int r0 = m_base + row;      if (r0 >= M) r0 = M - 1;
    int r1 = m_base + 16 + row; if (r1 >= M) r1 = M - 1;
    const _Float16* a0p = A + (size_t)r0 * K + kq;
    const _Float16* a1p = A + (size_t)r1 * K + kq;
    const _Float16* bp  = B + (size_t)(n_base + row) * K + kq;

    for (int k = 0; k < K; k += 32) {
        h8 a0 = *(const h8*)(a0p + k);
        h8 a1 = *(const h8*)(a1p + k);
        #pragma unroll
        for (int j = 0; j < NT; j++) {
            h8 b = *(const h8*)(bp + (size_t)j * 16 * K + k);
            acc[0][j] = __builtin_amdgcn_mfma_f32_16x16x32_f16(a0, b, acc[0][j], 0, 0, 0);
            acc[1][j] = __builtin_amdgcn_mfma_f32_16x16x32_f16(a1, b, acc[1][j], 0, 0, 0);
        }
    }

    const int col = lane & 15;
    const int rb = (lane >> 4) * 4;
    #pragma unroll
    for (int ms = 0; ms < 2; ms++) {
        #pragma unroll
        for (int j = 0; j < NT; j++) {
            #pragma unroll
            for (int r = 0; r < 4; r++) {
                int m = m_base + ms * 16 + rb + r;
                if (m < M) {
                    int n = n_base + j * 16 + col;
                    float v = acc[ms][j][r];
                    if (bias) v += bias[n];
                    if (Cf) Cf[(size_t)m * N + n] = v;
                    if (Ch) Ch[(size_t)m * N + n] = (_Float16)v;
                }
            }
        }
    }
}

// ---------------- per-node el/er ----------------

__global__ void node_elr_h(const _Float16* __restrict__ feat, const float* __restrict__ al,
                           const float* __restrict__ ar, float* __restrict__ el,
                           float* __restrict__ er, int nN) {
    int t = blockIdx.x * blockDim.x + threadIdx.x;
    if (t >= nN * 4) return;
    int n = t >> 2, h = t & 3;
    const _Float16* f = feat + (size_t)n * 256 + h * 64;
    const float* a = al + h * 64;
    const float* r = ar + h * 64;
    float sl = 0.f, sr = 0.f;
    #pragma unroll
    for (int j = 0; j < 64; j += 8) {
        h8 fv = *(const h8*)(f + j);
        #pragma unroll
        for (int q = 0; q < 8; q++) {
            float x = (float)fv[q];
            sl = fmaf(x, a[j + q], sl);
            sr = fmaf(x, r[j + q], sr);
        }
    }
    el[t] = sl; er[t] = sr;
}

__global__ void node_elr_f2(const float* __restrict__ feat, const float* __restrict__ al,
                            const float* __restrict__ ar, float* __restrict__ el,
                            float* __restrict__ er, int nN) {
    int t = blockIdx.x * blockDim.x + threadIdx.x;
    if (t >= nN) return;
    const float* f = feat + (size_t)t * 32;
    float sl = 0.f, sr = 0.f;
    #pragma unroll
    for (int j = 0; j < 16; j += 4) {
        float4 fv = *(const float4*)(f + j);
        float4 av = *(const float4*)(al + j);
        float4 rv = *(const float4*)(ar + j);
        sl += fv.x * av.x + fv.y * av.y + fv.z * av.z + fv.w * av.w;
        sr += fv.x * rv.x + fv.y * rv.y + fv.z * rv.z + fv.w * rv.w;
    }
    el[t] = sl; er[t] = sr;
}

// ---------------- fused GAT edge stage, H=4 ----------------
// one wave per dst node. Fast path (deg<=64): lane i owns edge i — single gather,
// in-register softmax; phase B = 32 feature-chunks x 2 edge-slots, h8 loads.
// NOTE: all __shfl calls execute under wave-uniform control flow (exec=full) —
// shfl from an exec-masked-off lane is undefined on CDNA (round-5 bug).

template<bool WRITE_A, bool HAS_PREV, bool HAS_RES>
__global__ __launch_bounds__(256) void gat_fused4(const int* __restrict__ rowstart,
                                                  const int* __restrict__ pk,
                                                  const float* __restrict__ el,
                                                  const float* __restrict__ er,
                                                  const float* __restrict__ es,
                                                  const _Float16* __restrict__ feat,
                                                  const float* __restrict__ aprev,
                                                  float* __restrict__ awrite,
                                                  const _Float16* __restrict__ resh,
                                                  _Float16* __restrict__ outh, int nN) {
    __shared__ float a_lds[4][256];
    const int wave = threadIdx.x >> 6;
    const int lane = threadIdx.x & 63;
    int n = blockIdx.x * 4 + wave;
    if (n >= nN) return;
    const int r0 = rowstart[n], r1 = rowstart[n + 1];
    const int deg = r1 - r0;
    float4 er4 = *(const float4*)(er + n * 4);

    if (deg <= 64) {
        // ---- phase A: one edge per lane, in-register softmax ----
        const int idx = r0 + lane;
        const bool act = idx < r1;
        int p = act ? pk[idx] : 0;
        int psrc = p & 0xFFFF;
        float4 v4 = {-INFINITY, -INFINITY, -INFINITY, -INFINITY};
        if (act) {
            float4 e4 = *(const float4*)(el + psrc * 4);
            float4 c4 = *(const float4*)(es + (p >> 16) * 4);
            float v;
            v = e4.x + er4.x + c4.x; v4.x = v > 0.f ? v : SLOPE * v;
            v = e4.y + er4.y + c4.y; v4.y = v > 0.f ? v : SLOPE * v;
            v = e4.z + er4.z + c4.z; v4.z = v > 0.f ? v : SLOPE * v;
            v = e4.w + er4.w + c4.w; v4.w = v > 0.f ? v : SLOPE * v;
        }
        float4 m4 = v4;
        #pragma unroll
        for (int off = 1; off < 64; off <<= 1) {
            m4.x = fmaxf(m4.x, __shfl_xor(m4.x, off));
            m4.y = fmaxf(m4.y, __shfl_xor(m4.y, off));
            m4.z = fmaxf(m4.z, __shfl_xor(m4.z, off));
            m4.w = fmaxf(m4.w, __shfl_xor(m4.w, off));
        }
        float4 ex = {0.f, 0.f, 0.f, 0.f};
        if (act) {
            ex.x = __expf(v4.x - m4.x);
            ex.y = __expf(v4.y - m4.y);
            ex.z = __expf(v4.z - m4.z);
            ex.w = __expf(v4.w - m4.w);
        }
        float4 s4 = ex;
        #pragma unroll
        for (int off = 1; off < 64; off <<= 1) {
            s4.x += __shfl_xor(s4.x, off);
            s4.y += __shfl_xor(s4.y, off);
            s4.z += __shfl_xor(s4.z, off);
            s4.w += __shfl_xor(s4.w, off);
        }
        float4 a4;
        a4.x = ex.x / (s4.x + 1e-9f);
        a4.y = ex.y / (s4.y + 1e-9f);
        a4.z = ex.z / (s4.z + 1e-9f);
        a4.w = ex.w / (s4.w + 1e-9f);
        if (HAS_PREV && act) {
            float4 pv = *(const float4*)(aprev + (size_t)idx * 4);
            a4.x = a4.x * (1.f - ALPHA) + ALPHA * pv.x;
            a4.y = a4.y * (1.f - ALPHA) + ALPHA * pv.y;
            a4.z = a4.z * (1.f - ALPHA) + ALPHA * pv.z;
            a4.w = a4.w * (1.f - ALPHA) + ALPHA * pv.w;
        }
        if (WRITE_A && act) *(float4*)(awrite + (size_t)idx * 4) = a4;
        *(float4*)&a_lds[wave][lane * 4] = a4;

        // ---- phase B: gather-aggregate, 2 edge-slots x 32 feature-chunks ----
        // all loops wave-uniform -> full exec for every __shfl
        const int half = lane >> 5;
        const int fl = lane & 31;
        const int h = fl >> 3;
        float acc8[8];
        #pragma unroll
        for (int q = 0; q < 8; q++) acc8[q] = 0.f;
        int i = r0;
        for (; i + 3 < r1; i += 4) {
            int j0 = (i - r0) + half;
            int j1 = j0 + 2;
            int s0 = __shfl(psrc, j0);
            int s1 = __shfl(psrc, j1);
            float a0 = a_lds[wave][j0 * 4 + h];
            float a1 = a_lds[wave][j1 * 4 + h];
            h8 f0 = *(const h8*)(feat + (size_t)s0 * 256 + fl * 8);
            h8 f1 = *(const h8*)(feat + (size_t)s1 * 256 + fl * 8);
            #pragma unroll
            for (int q = 0; q < 8; q++) acc8[q] = fmaf(a0, (float)f0[q], acc8[q]);
            #pragma unroll
            for (int q = 0; q < 8; q++) acc8[q] = fmaf(a1, (float)f1[q], acc8[q]);
        }
        for (; i + 1 < r1; i += 2) {
            int j0 = (i - r0) + half;
            int s0 = __shfl(psrc, j0);
            float a0 = a_lds[wave][j0 * 4 + h];
            h8 f0 = *(const h8*)(feat + (size_t)s0 * 256 + fl * 8);
            #pragma unroll
            for (int q = 0; q < 8; q++) acc8[q] = fmaf(a0, (float)f0[q], acc8[q]);
        }
        if (i < r1) {
            int j0 = i - r0;
            int s0 = __shfl(psrc, j0);
            float a0 = (half == 0) ? a_lds[wave][j0 * 4 + h] : 0.f;
            h8 f0 = *(const h8*)(feat + (size_t)s0 * 256 + fl * 8);
            #pragma unroll
            for (int q = 0; q < 8; q++) acc8[q] = fmaf(a0, (float)f0[q], acc8[q]);
        }
        #pragma unroll
        for (int q = 0; q < 8; q++) acc8[q] += __shfl_xor(acc8[q], 32);

        if (half == 0) {
            if (HAS_RES) {
                h8 rv = *(const h8*)(resh + (size_t)n * 256 + fl * 8);
                #pragma unroll
                for (int q = 0; q < 8; q++) acc8[q] += (float)rv[q];
            }
            #pragma unroll
            for (int q = 0; q < 8; q++) acc8[q] = acc8[q] > 0.f ? acc8[q] : expm1f(acc8[q]);
            h8 o;
            #pragma unroll
            for (int q = 0; q < 8; q++) o[q] = (_Float16)acc8[q];
            *(h8*)(outh + (size_t)n * 256 + fl * 8) = o;
        }
        return;
    }

    // ---------------- fallback: deg > 64 (two-pass, rare) ----------------
    float4 m4 = {-INFINITY, -INFINITY, -INFINITY, -INFINITY};
    for (int base = r0; base < r1; base += 64) {
        int idx = base + lane;
        if (idx < r1) {
            int p = pk[idx];
            float4 e4 = *(const float4*)(el + (p & 0xFFFF) * 4);
            float4 c4 = *(const float4*)(es + (p >> 16) * 4);
            float v;
            v = e4.x + er4.x + c4.x; v = v > 0.f ? v : SLOPE * v; m4.x = fmaxf(m4.x, v);
            v = e4.y + er4.y + c4.y; v = v > 0.f ? v : SLOPE * v; m4.y = fmaxf(m4.y, v);
            v = e4.z + er4.z + c4.z; v = v > 0.f ? v : SLOPE * v; m4.z = fmaxf(m4.z, v);
            v = e4.w + er4.w + c4.w; v = v > 0.f ? v : SLOPE * v; m4.w = fmaxf(m4.w, v);
        }
    }
    #pragma unroll
    for (int off = 1; off < 64; off <<= 1) {
        m4.x = fmaxf(m4.x, __shfl_xor(m4.x, off));
        m4.y = fmaxf(m4.y, __shfl_xor(m4.y, off));
        m4.z = fmaxf(m4.z, __shfl_xor(m4.z, off));
        m4.w = fmaxf(m4.w, __shfl_xor(m4.w, off));
    }
    float4 s4 = {0.f, 0.f, 0.f, 0.f};
    for (int base = r0; base < r1; base += 64) {
        int idx = base + lane;
        if (idx < r1) {
            int p = pk[idx];
            float4 e4 = *(const float4*)(el + (p & 0xFFFF) * 4);
            float4 c4 = *(const float4*)(es + (p >> 16) * 4);
            float4 exv;
            float v;
            v = e4.x + er4.x + c4.x; v = v > 0.f ? v : SLOPE * v; exv.x = __expf(v - m4.x);
            v = e4.y + er4.y + c4.y; v = v > 0.f ? v : SLOPE * v; exv.y = __expf(v - m4.y);
            v = e4.z + er4.z + c4.z; v = v > 0.f ? v : SLOPE * v; exv.z = __expf(v - m4.z);
            v = e4.w + er4.w + c4.w; v = v > 0.f ? v : SLOPE * v; exv.w = __expf(v - m4.w);
            if (base == r0) *(float4*)&a_lds[wave][lane * 4] = exv;
            s4.x += exv.x; s4.y += exv.y; s4.z += exv.z; s4.w += exv.w;
        }
    }
    #pragma unroll
    for (int off = 1; off < 64; off <<= 1) {
        s4.x += __shfl_xor(s4.x, off);
        s4.y += __shfl_xor(s4.y, off);
        s4.z += __shfl_xor(s4.z, off);
        s4.w += __shfl_xor(s4.w, off);
    }
    float4 inv4;
    inv4.x = 1.f / (s4.x + 1e-9f); inv4.y = 1.f / (s4.y + 1e-9f);
    inv4.z = 1.f / (s4.z + 1e-9f); inv4.w = 1.f / (s4.w + 1e-9f);
    {
        int idx = r0 + lane;   // deg > 64 -> always valid
        float4 a = *(const float4*)&a_lds[wave][lane * 4];
        a.x *= inv4.x; a.y *= inv4.y; a.z *= inv4.z; a.w *= inv4.w;
        if (HAS_PREV) {
            float4 pv = *(const float4*)(aprev + (size_t)idx * 4);
            a.x = a.x * (1.f - ALPHA) + ALPHA * pv.x;
            a.y = a.y * (1.f - ALPHA) + ALPHA * pv.y;
            a.z = a.z * (1.f - ALPHA) + ALPHA * pv.z;
            a.w = a.w * (1.f - ALPHA) + ALPHA * pv.w;
        }
        if (WRITE_A) *(float4*)(awrite + (size_t)idx * 4) = a;
        *(float4*)&a_lds[wave][lane * 4] = a;
    }
    if (WRITE_A) {
        for (int base = r0 + 64; base < r1; base += 64) {
            int idx = base + lane;
            if (idx < r1) {
                int p = pk[idx];
                float4 e4 = *(const float4*)(el + (p & 0xFFFF) * 4);
                float4 c4 = *(const float4*)(es + (p >> 16) * 4);
                float4 a;
                float v;
                v = e4.x + er4.x + c4.x; v = v > 0.f ? v : SLOPE * v; a.x = __expf(v - m4.x) * inv4.x;
                v = e4.y + er4.y + c4.y; v = v > 0.f ? v : SLOPE * v; a.y = __expf(v - m4.y) * inv4.y;
                v = e4.z + er4.z + c4.z; v = v > 0.f ? v : SLOPE * v; a.z = __expf(v - m4.z) * inv4.z;
                v = e4.w + er4.w + c4.w; v = v > 0.f ? v : SLOPE * v; a.w = __expf(v - m4.w) * inv4.w;
                if (HAS_PREV) {
                    float4 pv = *(const float4*)(aprev + (size_t)idx * 4);
                    a.x = a.x * (1.f - ALPHA) + ALPHA * pv.x;
                    a.y = a.y * (1.f - ALPHA) + ALPHA * pv.y;
                    a.z = a.z * (1.f - ALPHA) + ALPHA * pv.z;
                    a.w = a.w * (1.f - ALPHA) + ALPHA * pv.w;
                }
                *(float4*)(awrite + (size_t)idx * 4) = a;
            }
        }
    }
    const int h = lane >> 4;
    float4 acc = {0.f, 0.f, 0.f, 0.f};
    const int cap = r0 + 64;
    for (int i = r0; i < cap; i++) {
        int p = pk[i];
        float av = a_lds[wave][(i - r0) * 4 + h];
        h4 f = *(const h4*)(feat + (size_t)(p & 0xFFFF) * 256 + lane * 4);
        acc.x = fmaf(av, (float)f[0], acc.x);
        acc.y = fmaf(av, (float)f[1], acc.y);
        acc.z = fmaf(av, (float)f[2], acc.z);
        acc.w = fmaf(av, (float)f[3], acc.w);
    }
    {
        float mh = sel4(m4, h), invh = sel4(inv4, h), erh = sel4(er4, h);
        for (int i = cap; i < r1; i++) {
            int p = pk[i];
            int s = p & 0xFFFF, t = p >> 16;
            float v = el[s * 4 + h] + erh + es[t * 4 + h];
            v = v > 0.f ? v : SLOPE * v;
            float a = __expf(v - mh) * invh;
            if (HAS_PREV) a = a * (1.f - ALPHA) + ALPHA * aprev[(size_t)i * 4 + h];
            h4 f = *(const h4*)(feat + (size_t)s * 256 + lane * 4);
            acc.x = fmaf(a, (float)f[0], acc.x);
            acc.y = fmaf(a, (float)f[1], acc.y);
            acc.z = fmaf(a, (float)f[2], acc.z);
            acc.w = fmaf(a, (float)f[3], acc.w);
        }
    }
    if (HAS_RES) {
        h4 rv = *(const h4*)(resh + (size_t)n * 256 + lane * 4);
        acc.x += (float)rv[0]; acc.y += (float)rv[1];
        acc.z += (float)rv[2]; acc.w += (float)rv[3];
    }
    acc.x = acc.x > 0.f ? acc.x : expm1f(acc.x);
    acc.y = acc.y > 0.f ? acc.y : expm1f(acc.y);
    acc.z = acc.z > 0.f ? acc.z : expm1f(acc.z);
    acc.w = acc.w > 0.f ? acc.w : expm1f(acc.w);
    h4 o;
    o[0] = (_Float16)acc.x; o[1] = (_Float16)acc.y;
    o[2] = (_Float16)acc.z; o[3] = (_Float16)acc.w;
    *(h4*)(outh + (size_t)n * 256 + lane * 4) = o;
}

// ---------------- fused GAT layer 2 (H=1, C=16): one wave per node ----------------

__global__ __launch_bounds__(256) void gat_fused1(const int* __restrict__ rowstart,
                                                  const int* __restrict__ pk,
                                                  const float* __restrict__ el,
                                                  const float* __restrict__ er,
                                                  const float* __restrict__ es,
                                                  const float* __restrict__ cpack,
                                                  float* __restrict__ out, int nN) {
    const int wave = threadIdx.x >> 6;
    const int lane = threadIdx.x & 63;
    int n = blockIdx.x * 4 + wave;
    if (n >= nN) return;
    const int r0 = rowstart[n], r1 = rowstart[n + 1];
    const int deg = r1 - r0;
    const float ern = er[n];

    if (deg <= 64) {
        const int idx = r0 + lane;
        const bool act = idx < r1;
        int p = act ? pk[idx] : 0;
        int psrc = p & 0xFFFF;
        float v = -INFINITY;
        if (act) {
            float t = el[psrc] + ern + es[p >> 16];
            v = t > 0.f ? t : SLOPE * t;
        }
        float m = v;
        #pragma unroll
        for (int off = 1; off < 64; off <<= 1) m = fmaxf(m, __shfl_xor(m, off));
        float ex = act ? __expf(v - m) : 0.f;
        float s = ex;
        #pragma unroll
        for (int off = 1; off < 64; off <<= 1) s += __shfl_xor(s, off);
        float a = ex / (s + 1e-9f);

        const int eslot = lane >> 4, fl = lane & 15;
        float acc = 0.f;
        int i = r0;
        for (; i + 3 < r1; i += 4) {
            int j = (i - r0) + eslot;
            int sj = __shfl(psrc, j);
            float aj = __shfl(a, j);
            acc = fmaf(aj, cpack[(size_t)sj * 32 + fl], acc);
        }
        int rem = r1 - i;
        if (rem > 0) {   // wave-uniform branch: full exec for the shfls below
            int j = (i - r0) + (eslot < rem ? eslot : rem - 1);
            int sj = __shfl(psrc, j);
            float aj = __shfl(a, j);
            if (eslot >= rem) aj = 0.f;   // masked lanes contribute nothing
            acc = fmaf(aj, cpack[(size_t)sj * 32 + fl], acc);
        }
        acc += __shfl_xor(acc, 16);
        acc += __shfl_xor(acc, 32);
        if (lane < 16) out[(size_t)n * 16 + lane] = acc + cpack[(size_t)n * 32 + 16 + lane];
        return;
    }

    // fallback deg > 64 (rare)
    float m = -INFINITY;
    for (int base = r0; base < r1; base += 64) {
        int idx = base + lane;
        if (idx < r1) {
            int p = pk[idx];
            float v = el[p & 0xFFFF] + ern + es[p >> 16];
            v = v > 0.f ? v : SLOPE * v;
            m = fmaxf(m, v);
        }
    }
    #pragma unroll
    for (int off = 1; off < 64; off <<= 1) m = fmaxf(m, __shfl_xor(m, off));
    float s = 0.f;
    for (int base = r0; base < r1; base += 64) {
        int idx = base + lane;
        if (idx < r1) {
            int p = pk[idx];
            float v = el[p & 0xFFFF] + ern + es[p >> 16];
            v = v > 0.f ? v : SLOPE * v;
            s += __expf(v - m);
        }
    }
    #pragma unroll
    for (int off = 1; off < 64; off <<= 1) s += __shfl_xor(s, off);
    float inv = 1.f / (s + 1e-9f);
    const int eslot = lane >> 4, fl = lane & 15;
    float acc = 0.f;
    for (int i = r0; i < r1; i += 4) {
        int rem = r1 - i;
        if (eslot < rem) {   // no shfl inside: divergence safe
            int j = i + eslot;
            int p = pk[j];
            float v = el[p & 0xFFFF] + ern + es[p >> 16];
            v = v > 0.f ? v : SLOPE * v;
            float a = __expf(v - m) * inv;
            acc = fmaf(a, cpack[(size_t)(p & 0xFFFF) * 32 + fl], acc);
        }
    }
    acc += __shfl_xor(acc, 16);
    acc += __shfl_xor(acc, 32);
    if (lane < 16) out[(size_t)n * 16 + lane] = acc + cpack[(size_t)n * 32 + 16 + lane];
}

// ---------------- host ----------------

extern "C" void kernel_launch(void* const* d_in, const int* in_sizes, int n_in,
                              void* d_out, int out_size, void* d_ws, size_t ws_size,
                              hipStream_t stream) {
    const float* x0 = (const float*)d_in[0];
    const float* x1 = (const float*)d_in[1];
    const float* x2 = (const float*)d_in[2];
    const int* src  = (const int*)d_in[3];
    const int* dst  = (const int*)d_in[4];
    const int* et   = (const int*)d_in[5];
    const float* W0 = (const float*)d_in[6];  const float* b0 = (const float*)d_in[7];
    const float* W1 = (const float*)d_in[8];  const float* b1 = (const float*)d_in[9];
    const float* W2 = (const float*)d_in[10]; const float* b2 = (const float*)d_in[11];
    const float* Wg0 = (const float*)d_in[12]; const float* etab0 = (const float*)d_in[13];
    const float* We0 = (const float*)d_in[14]; const float* al0 = (const float*)d_in[15];
    const float* ar0 = (const float*)d_in[16]; const float* ae0 = (const float*)d_in[17];
    const float* Wg1 = (const float*)d_in[18]; const float* etab1 = (const float*)d_in[19];
    const float* We1 = (const float*)d_in[20]; const float* al1 = (const float*)d_in[21];
    const float* ar1 = (const float*)d_in[22]; const float* ae1 = (const float*)d_in[23];
    const float* Wg2 = (const float*)d_in[24]; const float* etab2 = (const float*)d_in[25];
    const float* We2 = (const float*)d_in[26]; const float* al2 = (const float*)d_in[27];
    const float* ar2 = (const float*)d_in[28]; const float* ae2 = (const float*)d_in[29];
    const float* resW2 = (const float*)d_in[30];
    float* outp = (float*)d_out;

    char* p = (char*)d_ws;
    auto alloc = [&](size_t bytes) -> void* {
        void* r = (void*)p;
        p += (bytes + 255) & ~(size_t)255;
        return r;
    };
    _Float16* x0h   = (_Float16*)alloc((size_t)N0 * 128 * 2);
    _Float16* x1h   = (_Float16*)alloc((size_t)N1 * 64 * 2);
    _Float16* x2h   = (_Float16*)alloc((size_t)N2 * 32 * 2);
    _Float16* W0h   = (_Float16*)alloc(64 * 128 * 2);
    _Float16* W1h   = (_Float16*)alloc(64 * 64 * 2);
    _Float16* W2h   = (_Float16*)alloc(64 * 32 * 2);
    _Float16* Wg0h  = (_Float16*)alloc(256 * 64 * 2);
    _Float16* Wg1h  = (_Float16*)alloc(256 * 256 * 2);
    _Float16* wpkh  = (_Float16*)alloc(32 * 256 * 2);
    _Float16* h0h   = (_Float16*)alloc((size_t)NN * 64 * 2);
    _Float16* feath = (_Float16*)alloc((size_t)NN * 256 * 2);
    _Float16* bufAh = (_Float16*)alloc((size_t)NN * 256 * 2);
    _Float16* bufBh = (_Float16*)alloc((size_t)NN * 256 * 2);
    float* el    = (float*)alloc((size_t)NN * 4 * 4);
    float* er    = (float*)alloc((size_t)NN * 4 * 4);
    float* a0    = (float*)alloc((size_t)EE * 4 * 4);
    float* es    = (float*)alloc(96 * 4);
    float* cpack = (float*)alloc((size_t)NN * 32 * 4);
    int* rowstart = (int*)alloc((size_t)(NN + 1) * 4);
    int* deg      = (int*)alloc((size_t)NN * 4);
    int* cursor   = (int*)alloc((size_t)NN * 4);
    int* bsum     = (int*)alloc(256 * 4);
    int* pk       = (int*)alloc((size_t)EE * 4);

    const int EB = (EE + 255) / 256;        // 3125
    const int NB = (NN + 255) / 256;        // 196
    const int NHB = (NN * 4 + 255) / 256;   // 782
    const int MB128 = (NN + 127) / 128;     // 391
    const int WB = (NN + 3) / 4;            // 12500

    // CSR build
    hipMemsetAsync(deg, 0, (size_t)NN * 4, stream);
    hist_kernel<<<EB, 256, 0, stream>>>(dst, deg, EE);
    block_sum_kernel<<<NB, 256, 0, stream>>>(deg, bsum, NN);
    scan_bsum_kernel<<<1, 256, 0, stream>>>(bsum, NB);
    scan_out_kernel<<<NB, 256, 0, stream>>>(deg, bsum, rowstart, cursor, NN);
    scatter_kernel<<<EB, 256, 0, stream>>>(src, dst, et, cursor, pk, EE);

    // es tables + weight/feature converts
    es_table_all<<<72, 64, 0, stream>>>(etab0, We0, ae0, etab1, We1, ae1, etab2, We2, ae2, es);
    {
        int n0c = N0 * 128, n1c = N1 * 64, n2c = N2 * 32;
        int total = n0c + n1c + n2c + 8192 + 4096 + 2048 + 16384 + 65536 + 4096 + 4096;
        f2h10<<<(total + 255) / 256, 256, 0, stream>>>(
            x0, x0h, n0c, x1, x1h, n1c, x2, x2h, n2c,
            W0, W0h, 8192, W1, W1h, 4096, W2, W2h, 2048,
            Wg0, Wg0h, 16384, Wg1, Wg1h, 65536,
            Wg2, wpkh, 4096, resW2, wpkh + 4096, 4096);
    }

    // input projections -> h0h [N,64] fp16
    gemm_mfma<4><<<dim3((N0 + 127) / 128, 1), 256, 0, stream>>>(x0h, W0h, b0, nullptr, h0h, N0, 64, 128);
    gemm_mfma<4><<<dim3((N1 + 127) / 128, 1), 256, 0, stream>>>(x1h, W1h, b1, nullptr, h0h + (size_t)N0 * 64, N1, 64, 64);
    gemm_mfma<4><<<dim3((N2 + 127) / 128, 1), 256, 0, stream>>>(x2h, W2h, b2, nullptr, h0h + (size_t)(N0 + N1) * 64, N2, 64, 32);

    // ---- GAT layer 0 ----
    gemm_mfma<8><<<dim3(MB128, 2), 256, 0, stream>>>(h0h, Wg0h, nullptr, nullptr, feath, NN, 256, 64);
    node_elr_h<<<NHB, 256, 0, stream>>>(feath, al0, ar0, el, er, NN);
    gat_fused4<true, false, false><<<WB, 256, 0, stream>>>(
        rowstart, pk, el, er, es + 0, feath, nullptr, a0, nullptr, bufAh, NN);

    // ---- GAT layer 1 ----
    gemm_mfma<8><<<dim3(MB128, 2), 256, 0, stream>>>(bufAh, Wg1h, nullptr, nullptr, feath, NN, 256, 256);
    node_elr_h<<<NHB, 256, 0, stream>>>(feath, al1, ar1, el, er, NN);
    gat_fused4<false, true, true><<<WB, 256, 0, stream>>>(
        rowstart, pk, el, er, es + 32, feath, a0, nullptr, bufAh, bufBh, NN);

    // ---- GAT layer 2 (H=1, C=16, linear residual, no act) ----
    gemm_mfma<2><<<dim3(MB128, 1), 256, 0, stream>>>(bufBh, wpkh, nullptr, cpack, nullptr, NN, 32, 256);
    node_elr_f2<<<NB, 256, 0, stream>>>(cpack, al2, ar2, el, er, NN);
    gat_fused1<<<WB, 256, 0, stream>>>(rowstart, pk, el, er, es + 64, cpack, outp, NN);
}

// Round 7
// 524.088 us; speedup vs baseline: 2.4036x; 1.0244x over previous
//
#include <hip/hip_runtime.h>
#include <math.h>

#define N0 20000
#define N1 15000
#define N2 15000
#define NN 50000          // total nodes
#define EE 800000         // edges
#define SLOPE 0.2f
#define ALPHA 0.05f

typedef _Float16 h8 __attribute__((ext_vector_type(8)));
typedef _Float16 h4 __attribute__((ext_vector_type(4)));
typedef float f4v __attribute__((ext_vector_type(4)));

__device__ __forceinline__ float sel4(float4 v, int h) {
    float lo = (h & 1) ? v.y : v.x;
    float hi = (h & 1) ? v.w : v.z;
    return (h & 2) ? hi : lo;
}

// ---------------- CSR build ----------------

__global__ void hist_kernel(const int* __restrict__ dst, int* __restrict__ deg, int E_) {
    int e = blockIdx.x * blockDim.x + threadIdx.x;
    if (e < E_) atomicAdd(&deg[dst[e]], 1);
}

__global__ __launch_bounds__(256) void block_sum_kernel(const int* __restrict__ deg,
                                                        int* __restrict__ bsum, int n) {
    int i = blockIdx.x * 256 + threadIdx.x;
    int v = (i < n) ? deg[i] : 0;
    #pragma unroll
    for (int off = 32; off > 0; off >>= 1) v += __shfl_down(v, off);
    __shared__ int sh[4];
    if ((threadIdx.x & 63) == 0) sh[threadIdx.x >> 6] = v;
    __syncthreads();
    if (threadIdx.x == 0) bsum[blockIdx.x] = sh[0] + sh[1] + sh[2] + sh[3];
}

__global__ __launch_bounds__(256) void scan_bsum_kernel(int* __restrict__ bsum, int nb) {
    __shared__ int sh[256];
    int tid = threadIdx.x;
    int v = (tid < nb) ? bsum[tid] : 0;
    sh[tid] = v;
    __syncthreads();
    #pragma unroll
    for (int off = 1; off < 256; off <<= 1) {
        int t = (tid >= off) ? sh[tid - off] : 0;
        __syncthreads();
        sh[tid] += t;
        __syncthreads();
    }
    if (tid < nb) bsum[tid] = sh[tid] - v;   // exclusive
}

__global__ __launch_bounds__(256) void scan_out_kernel(const int* __restrict__ deg,
                                                       const int* __restrict__ boff,
                                                       int* __restrict__ rowstart,
                                                       int* __restrict__ cursor, int n) {
    __shared__ int sh[256];
    int tid = threadIdx.x;
    int i = blockIdx.x * 256 + tid;
    int v = (i < n) ? deg[i] : 0;
    sh[tid] = v;
    __syncthreads();
    #pragma unroll
    for (int off = 1; off < 256; off <<= 1) {
        int t = (tid >= off) ? sh[tid - off] : 0;
        __syncthreads();
        sh[tid] += t;
        __syncthreads();
    }
    int excl = sh[tid] - v + boff[blockIdx.x];
    if (i < n) { rowstart[i] = excl; cursor[i] = excl; }
    if (i == n - 1) rowstart[n] = excl + v;
}

// pack (et<<16)|src into one int per CSR slot
__global__ void scatter_kernel(const int* __restrict__ src, const int* __restrict__ dst,
                               const int* __restrict__ et, int* __restrict__ cursor,
                               int* __restrict__ pk, int E_) {
    int e = blockIdx.x * blockDim.x + threadIdx.x;
    if (e >= E_) return;
    int d = dst[e];
    int p = atomicAdd(&cursor[d], 1);
    pk[p] = (et[e] << 16) | src[e];
}

// ---------------- es tables (all 3 layers, one launch) ----------------

__global__ void es_table_all(const float* __restrict__ etab0, const float* __restrict__ We0,
                             const float* __restrict__ ae0,
                             const float* __restrict__ etab1, const float* __restrict__ We1,
                             const float* __restrict__ ae1,
                             const float* __restrict__ etab2, const float* __restrict__ We2,
                             const float* __restrict__ ae2,
                             float* __restrict__ es) {
    int b = blockIdx.x;
    const float *etab, *We, *ae;
    float* out;
    int H;
    if (b < 32)      { etab = etab0; We = We0; ae = ae0; out = es;      H = 4; }
    else if (b < 64) { b -= 32; etab = etab1; We = We1; ae = ae1; out = es + 32; H = 4; }
    else             { b -= 64; etab = etab2; We = We2; ae = ae2; out = es + 64; H = 1; }
    int t = b / H, h = b % H;
    int j = threadIdx.x;   // 0..63
    const float* w = We + (size_t)(h * 64 + j) * 64;
    const float* e = etab + t * 64;
    float s = 0.f;
    #pragma unroll
    for (int k = 0; k < 64; k += 4) {
        float4 wv = *(const float4*)(w + k);
        float4 ev = *(const float4*)(e + k);
        s += wv.x * ev.x + wv.y * ev.y + wv.z * ev.z + wv.w * ev.w;
    }
    s *= ae[h * 64 + j];
    #pragma unroll
    for (int off = 32; off > 0; off >>= 1) s += __shfl_down(s, off);
    if (j == 0) out[t * H + h] = s;
}

// ---------------- fp32 -> fp16 converts (10 arrays, one launch) ----------------

__global__ void f2h10(const float* s0, _Float16* d0, int n0,
                      const float* s1, _Float16* d1, int n1,
                      const float* s2, _Float16* d2, int n2,
                      const float* s3, _Float16* d3, int n3,
                      const float* s4, _Float16* d4, int n4,
                      const float* s5, _Float16* d5, int n5,
                      const float* s6, _Float16* d6, int n6,
                      const float* s7, _Float16* d7, int n7,
                      const float* s8, _Float16* d8, int n8,
                      const float* s9, _Float16* d9, int n9) {
    int t = blockIdx.x * 256 + threadIdx.x;
    if (t < n0) { d0[t] = (_Float16)s0[t]; return; } t -= n0;
    if (t < n1) { d1[t] = (_Float16)s1[t]; return; } t -= n1;
    if (t < n2) { d2[t] = (_Float16)s2[t]; return; } t -= n2;
    if (t < n3) { d3[t] = (_Float16)s3[t]; return; } t -= n3;
    if (t < n4) { d4[t] = (_Float16)s4[t]; return; } t -= n4;
    if (t < n5) { d5[t] = (_Float16)s5[t]; return; } t -= n5;
    if (t < n6) { d6[t] = (_Float16)s6[t]; return; } t -= n6;
    if (t < n7) { d7[t] = (_Float16)s7[t]; return; } t -= n7;
    if (t < n8) { d8[t] = (_Float16)s8[t]; return; } t -= n8;
    if (t < n9) { d9[t] = (_Float16)s9[t]; }
}

// ---------------- MFMA fp16 GEMM (verified) ----------------

template<int NT>
__global__ __launch_bounds__(256) void gemm_mfma(const _Float16* __restrict__ A,
                                                 const _Float16* __restrict__ B,
                                                 const float* __restrict__ bias,
                                                 float* __restrict__ Cf,
                                                 _Float16* __restrict__ Ch,
                                                 int M, int N, int K) {
    const int wave = threadIdx.x >> 6;
    const int lane = threadIdx.x & 63;
    const int m_base = (blockIdx.x * 4 + wave) * 32;
    const int n_base = blockIdx.y * (NT * 16);
    const int row = lane & 15;
    const int kq = (lane >> 4) * 8;

    f4v acc[2][NT];
    #pragma unroll
    for (int i = 0; i < 2; i++)
        #pragma unroll
        for (int j = 0; j < NT; j++) {
            f4v z = {0.f, 0.f, 0.f, 0.f};
            acc[i][j] = z;
        }

    int r0 = m_base + row;      if (r0 >= M) r0 = M - 1;
    int r1 = m_base + 16 + row; if (r1 >= M) r1 = M - 1;
    const _Float16* a0p = A + (size_t)r0 * K + kq;
    const _Float16* a1p = A + (size_t)r1 * K + kq;
    const _Float16* bp  = B + (size_t)(n_base + row) * K + kq;

    for (int k = 0; k < K; k += 32) {
        h8 a0 = *(const h8*)(a0p + k);
        h8 a1 = *(const h8*)(a1p + k);
        #pragma unroll
        for (int j = 0; j < NT; j++) {
            h8 b = *(const h8*)(bp + (size_t)j * 16 * K + k);
            acc[0][j] = __builtin_amdgcn_mfma_f32_16x16x32_f16(a0, b, acc[0][j], 0, 0, 0);
            acc[1][j] = __builtin_amdgcn_mfma_f32_16x16x32_f16(a1, b, acc[1][j], 0, 0, 0);
        }
    }

    const int col = lane & 15;
    const int rb = (lane >> 4) * 4;
    #pragma unroll
    for (int ms = 0; ms < 2; ms++) {
        #pragma unroll
        for (int j = 0; j < NT; j++) {
            #pragma unroll
            for (int r = 0; r < 4; r++) {
                int m = m_base + ms * 16 + rb + r;
                if (m < M) {
                    int n = n_base + j * 16 + col;
                    float v = acc[ms][j][r];
                    if (bias) v += bias[n];
                    if (Cf) Cf[(size_t)m * N + n] = v;
                    if (Ch) Ch[(size_t)m * N + n] = (_Float16)v;
                }
            }
        }
    }
}

// ---------------- per-node el/er ----------------

__global__ void node_elr_h(const _Float16* __restrict__ feat, const float* __restrict__ al,
                           const float* __restrict__ ar, float* __restrict__ el,
                           float* __restrict__ er, int nN) {
    int t = blockIdx.x * blockDim.x + threadIdx.x;
    if (t >= nN * 4) return;
    int n = t >> 2, h = t & 3;
    const _Float16* f = feat + (size_t)n * 256 + h * 64;
    const float* a = al + h * 64;
    const float* r = ar + h * 64;
    float sl = 0.f, sr = 0.f;
    #pragma unroll
    for (int j = 0; j < 64; j += 8) {
        h8 fv = *(const h8*)(f + j);
        #pragma unroll
        for (int q = 0; q < 8; q++) {
            float x = (float)fv[q];
            sl = fmaf(x, a[j + q], sl);
            sr = fmaf(x, r[j + q], sr);
        }
    }
    el[t] = sl; er[t] = sr;
}

__global__ void node_elr_f2(const float* __restrict__ feat, const float* __restrict__ al,
                            const float* __restrict__ ar, float* __restrict__ el,
                            float* __restrict__ er, int nN) {
    int t = blockIdx.x * blockDim.x + threadIdx.x;
    if (t >= nN) return;
    const float* f = feat + (size_t)t * 32;
    float sl = 0.f, sr = 0.f;
    #pragma unroll
    for (int j = 0; j < 16; j += 4) {
        float4 fv = *(const float4*)(f + j);
        float4 av = *(const float4*)(al + j);
        float4 rv = *(const float4*)(ar + j);
        sl += fv.x * av.x + fv.y * av.y + fv.z * av.z + fv.w * av.w;
        sr += fv.x * rv.x + fv.y * rv.y + fv.z * rv.z + fv.w * rv.w;
    }
    el[t] = sl; er[t] = sr;
}

// ---------------- fused GAT edge stage, H=4 ----------------
// one wave per dst node. Fast path (deg<=64): lane i owns edge i — single gather,
// in-register softmax; phase B = 32 feature-chunks x 2 edge-slots, h8 loads,
// unroll-4 (8 edges / iter -> 4 loads in flight per lane).
// NOTE: all __shfl calls execute under wave-uniform control flow (exec=full) —
// shfl from an exec-masked-off lane is undefined on CDNA (round-5 bug).

template<bool WRITE_A, bool HAS_PREV, bool HAS_RES>
__global__ __launch_bounds__(256) void gat_fused4(const int* __restrict__ rowstart,
                                                  const int* __restrict__ pk,
                                                  const float* __restrict__ el,
                                                  const float* __restrict__ er,
                                                  const float* __restrict__ es,
                                                  const _Float16* __restrict__ feat,
                                                  const _Float16* __restrict__ aprev,
                                                  _Float16* __restrict__ awrite,
                                                  const _Float16* __restrict__ resh,
                                                  _Float16* __restrict__ outh, int nN) {
    __shared__ float a_lds[4][256];
    const int wave = threadIdx.x >> 6;
    const int lane = threadIdx.x & 63;
    int n = blockIdx.x * 4 + wave;
    if (n >= nN) return;
    const int r0 = rowstart[n], r1 = rowstart[n + 1];
    const int deg = r1 - r0;
    float4 er4 = *(const float4*)(er + n * 4);

    if (deg <= 64) {
        // ---- phase A: one edge per lane, in-register softmax ----
        const int idx = r0 + lane;
        const bool act = idx < r1;
        int p = act ? pk[idx] : 0;
        int psrc = p & 0xFFFF;
        float4 v4 = {-INFINITY, -INFINITY, -INFINITY, -INFINITY};
        if (act) {
            float4 e4 = *(const float4*)(el + psrc * 4);
            float4 c4 = *(const float4*)(es + (p >> 16) * 4);
            float v;
            v = e4.x + er4.x + c4.x; v4.x = v > 0.f ? v : SLOPE * v;
            v = e4.y + er4.y + c4.y; v4.y = v > 0.f ? v : SLOPE * v;
            v = e4.z + er4.z + c4.z; v4.z = v > 0.f ? v : SLOPE * v;
            v = e4.w + er4.w + c4.w; v4.w = v > 0.f ? v : SLOPE * v;
        }
        float4 m4 = v4;
        #pragma unroll
        for (int off = 1; off < 64; off <<= 1) {
            m4.x = fmaxf(m4.x, __shfl_xor(m4.x, off));
            m4.y = fmaxf(m4.y, __shfl_xor(m4.y, off));
            m4.z = fmaxf(m4.z, __shfl_xor(m4.z, off));
            m4.w = fmaxf(m4.w, __shfl_xor(m4.w, off));
        }
        float4 ex = {0.f, 0.f, 0.f, 0.f};
        if (act) {
            ex.x = __expf(v4.x - m4.x);
            ex.y = __expf(v4.y - m4.y);
            ex.z = __expf(v4.z - m4.z);
            ex.w = __expf(v4.w - m4.w);
        }
        float4 s4 = ex;
        #pragma unroll
        for (int off = 1; off < 64; off <<= 1) {
            s4.x += __shfl_xor(s4.x, off);
            s4.y += __shfl_xor(s4.y, off);
            s4.z += __shfl_xor(s4.z, off);
            s4.w += __shfl_xor(s4.w, off);
        }
        float4 a4;
        a4.x = ex.x / (s4.x + 1e-9f);
        a4.y = ex.y / (s4.y + 1e-9f);
        a4.z = ex.z / (s4.z + 1e-9f);
        a4.w = ex.w / (s4.w + 1e-9f);
        if (HAS_PREV && act) {
            h4 pv = *(const h4*)(aprev + (size_t)idx * 4);
            a4.x = a4.x * (1.f - ALPHA) + ALPHA * (float)pv[0];
            a4.y = a4.y * (1.f - ALPHA) + ALPHA * (float)pv[1];
            a4.z = a4.z * (1.f - ALPHA) + ALPHA * (float)pv[2];
            a4.w = a4.w * (1.f - ALPHA) + ALPHA * (float)pv[3];
        }
        if (WRITE_A && act) {
            h4 aw;
            aw[0] = (_Float16)a4.x; aw[1] = (_Float16)a4.y;
            aw[2] = (_Float16)a4.z; aw[3] = (_Float16)a4.w;
            *(h4*)(awrite + (size_t)idx * 4) = aw;
        }
        *(float4*)&a_lds[wave][lane * 4] = a4;

        // ---- phase B: gather-aggregate, 2 edge-slots x 32 feature-chunks, unroll-4 ----
        // all loops wave-uniform -> full exec for every __shfl
        const int half = lane >> 5;
        const int fl = lane & 31;
        const int h = fl >> 3;
        float acc8[8];
        #pragma unroll
        for (int q = 0; q < 8; q++) acc8[q] = 0.f;
        int i = r0;
        for (; i + 7 < r1; i += 8) {
            int j0 = (i - r0) + half;
            int j1 = j0 + 2, j2 = j0 + 4, j3 = j0 + 6;
            int s0 = __shfl(psrc, j0);
            int s1 = __shfl(psrc, j1);
            int s2 = __shfl(psrc, j2);
            int s3 = __shfl(psrc, j3);
            float a0 = a_lds[wave][j0 * 4 + h];
            float a1 = a_lds[wave][j1 * 4 + h];
            float a2 = a_lds[wave][j2 * 4 + h];
            float a3 = a_lds[wave][j3 * 4 + h];
            h8 f0 = *(const h8*)(feat + (size_t)s0 * 256 + fl * 8);
            h8 f1 = *(const h8*)(feat + (size_t)s1 * 256 + fl * 8);
            h8 f2 = *(const h8*)(feat + (size_t)s2 * 256 + fl * 8);
            h8 f3 = *(const h8*)(feat + (size_t)s3 * 256 + fl * 8);
            #pragma unroll
            for (int q = 0; q < 8; q++) acc8[q] = fmaf(a0, (float)f0[q], acc8[q]);
            #pragma unroll
            for (int q = 0; q < 8; q++) acc8[q] = fmaf(a1, (float)f1[q], acc8[q]);
            #pragma unroll
            for (int q = 0; q < 8; q++) acc8[q] = fmaf(a2, (float)f2[q], acc8[q]);
            #pragma unroll
            for (int q = 0; q < 8; q++) acc8[q] = fmaf(a3, (float)f3[q], acc8[q]);
        }
        for (; i + 3 < r1; i += 4) {
            int j0 = (i - r0) + half;
            int j1 = j0 + 2;
            int s0 = __shfl(psrc, j0);
            int s1 = __shfl(psrc, j1);
            float a0 = a_lds[wave][j0 * 4 + h];
            float a1 = a_lds[wave][j1 * 4 + h];
            h8 f0 = *(const h8*)(feat + (size_t)s0 * 256 + fl * 8);
            h8 f1 = *(const h8*)(feat + (size_t)s1 * 256 + fl * 8);
            #pragma unroll
            for (int q = 0; q < 8; q++) acc8[q] = fmaf(a0, (float)f0[q], acc8[q]);
            #pragma unroll
            for (int q = 0; q < 8; q++) acc8[q] = fmaf(a1, (float)f1[q], acc8[q]);
        }
        for (; i + 1 < r1; i += 2) {
            int j0 = (i - r0) + half;
            int s0 = __shfl(psrc, j0);
            float a0 = a_lds[wave][j0 * 4 + h];
            h8 f0 = *(const h8*)(feat + (size_t)s0 * 256 + fl * 8);
            #pragma unroll
            for (int q = 0; q < 8; q++) acc8[q] = fmaf(a0, (float)f0[q], acc8[q]);
        }
        if (i < r1) {
            int j0 = i - r0;
            int s0 = __shfl(psrc, j0);
            float a0 = (half == 0) ? a_lds[wave][j0 * 4 + h] : 0.f;
            h8 f0 = *(const h8*)(feat + (size_t)s0 * 256 + fl * 8);
            #pragma unroll
            for (int q = 0; q < 8; q++) acc8[q] = fmaf(a0, (float)f0[q], acc8[q]);
        }
        #pragma unroll
        for (int q = 0; q < 8; q++) acc8[q] += __shfl_xor(acc8[q], 32);

        if (half == 0) {
            if (HAS_RES) {
                h8 rv = *(const h8*)(resh + (size_t)n * 256 + fl * 8);
                #pragma unroll
                for (int q = 0; q < 8; q++) acc8[q] += (float)rv[q];
            }
            #pragma unroll
            for (int q = 0; q < 8; q++) acc8[q] = acc8[q] > 0.f ? acc8[q] : expm1f(acc8[q]);
            h8 o;
            #pragma unroll
            for (int q = 0; q < 8; q++) o[q] = (_Float16)acc8[q];
            *(h8*)(outh + (size_t)n * 256 + fl * 8) = o;
        }
        return;
    }

    // ---------------- fallback: deg > 64 (two-pass, rare) ----------------
    float4 m4 = {-INFINITY, -INFINITY, -INFINITY, -INFINITY};
    for (int base = r0; base < r1; base += 64) {
        int idx = base + lane;
        if (idx < r1) {
            int p = pk[idx];
            float4 e4 = *(const float4*)(el + (p & 0xFFFF) * 4);
            float4 c4 = *(const float4*)(es + (p >> 16) * 4);
            float v;
            v = e4.x + er4.x + c4.x; v = v > 0.f ? v : SLOPE * v; m4.x = fmaxf(m4.x, v);
            v = e4.y + er4.y + c4.y; v = v > 0.f ? v : SLOPE * v; m4.y = fmaxf(m4.y, v);
            v = e4.z + er4.z + c4.z; v = v > 0.f ? v : SLOPE * v; m4.z = fmaxf(m4.z, v);
            v = e4.w + er4.w + c4.w; v = v > 0.f ? v : SLOPE * v; m4.w = fmaxf(m4.w, v);
        }
    }
    #pragma unroll
    for (int off = 1; off < 64; off <<= 1) {
        m4.x = fmaxf(m4.x, __shfl_xor(m4.x, off));
        m4.y = fmaxf(m4.y, __shfl_xor(m4.y, off));
        m4.z = fmaxf(m4.z, __shfl_xor(m4.z, off));
        m4.w = fmaxf(m4.w, __shfl_xor(m4.w, off));
    }
    float4 s4 = {0.f, 0.f, 0.f, 0.f};
    for (int base = r0; base < r1; base += 64) {
        int idx = base + lane;
        if (idx < r1) {
            int p = pk[idx];
            float4 e4 = *(const float4*)(el + (p & 0xFFFF) * 4);
            float4 c4 = *(const float4*)(es + (p >> 16) * 4);
            float4 exv;
            float v;
            v = e4.x + er4.x + c4.x; v = v > 0.f ? v : SLOPE * v; exv.x = __expf(v - m4.x);
            v = e4.y + er4.y + c4.y; v = v > 0.f ? v : SLOPE * v; exv.y = __expf(v - m4.y);
            v = e4.z + er4.z + c4.z; v = v > 0.f ? v : SLOPE * v; exv.z = __expf(v - m4.z);
            v = e4.w + er4.w + c4.w; v = v > 0.f ? v : SLOPE * v; exv.w = __expf(v - m4.w);
            if (base == r0) *(float4*)&a_lds[wave][lane * 4] = exv;
            s4.x += exv.x; s4.y += exv.y; s4.z += exv.z; s4.w += exv.w;
        }
    }
    #pragma unroll
    for (int off = 1; off < 64; off <<= 1) {
        s4.x += __shfl_xor(s4.x, off);
        s4.y += __shfl_xor(s4.y, off);
        s4.z += __shfl_xor(s4.z, off);
        s4.w += __shfl_xor(s4.w, off);
    }
    float4 inv4;
    inv4.x = 1.f / (s4.x + 1e-9f); inv4.y = 1.f / (s4.y + 1e-9f);
    inv4.z = 1.f / (s4.z + 1e-9f); inv4.w = 1.f / (s4.w + 1e-9f);
    {
        int idx = r0 + lane;   // deg > 64 -> always valid
        float4 a = *(const float4*)&a_lds[wave][lane * 4];
        a.x *= inv4.x; a.y *= inv4.y; a.z *= inv4.z; a.w *= inv4.w;
        if (HAS_PREV) {
            h4 pv = *(const h4*)(aprev + (size_t)idx * 4);
            a.x = a.x * (1.f - ALPHA) + ALPHA * (float)pv[0];
            a.y = a.y * (1.f - ALPHA) + ALPHA * (float)pv[1];
            a.z = a.z * (1.f - ALPHA) + ALPHA * (float)pv[2];
            a.w = a.w * (1.f - ALPHA) + ALPHA * (float)pv[3];
        }
        if (WRITE_A) {
            h4 aw;
            aw[0] = (_Float16)a.x; aw[1] = (_Float16)a.y;
            aw[2] = (_Float16)a.z; aw[3] = (_Float16)a.w;
            *(h4*)(awrite + (size_t)idx * 4) = aw;
        }
        *(float4*)&a_lds[wave][lane * 4] = a;
    }
    if (WRITE_A) {
        for (int base = r0 + 64; base < r1; base += 64) {
            int idx = base + lane;
            if (idx < r1) {
                int p = pk[idx];
                float4 e4 = *(const float4*)(el + (p & 0xFFFF) * 4);
                float4 c4 = *(const float4*)(es + (p >> 16) * 4);
                float4 a;
                float v;
                v = e4.x + er4.x + c4.x; v = v > 0.f ? v : SLOPE * v; a.x = __expf(v - m4.x) * inv4.x;
                v = e4.y + er4.y + c4.y; v = v > 0.f ? v : SLOPE * v; a.y = __expf(v - m4.y) * inv4.y;
                v = e4.z + er4.z + c4.z; v = v > 0.f ? v : SLOPE * v; a.z = __expf(v - m4.z) * inv4.z;
                v = e4.w + er4.w + c4.w; v = v > 0.f ? v : SLOPE * v; a.w = __expf(v - m4.w) * inv4.w;
                if (HAS_PREV) {
                    h4 pv = *(const h4*)(aprev + (size_t)idx * 4);
                    a.x = a.x * (1.f - ALPHA) + ALPHA * (float)pv[0];
                    a.y = a.y * (1.f - ALPHA) + ALPHA * (float)pv[1];
                    a.z = a.z * (1.f - ALPHA) + ALPHA * (float)pv[2];
                    a.w = a.w * (1.f - ALPHA) + ALPHA * (float)pv[3];
                }
                h4 aw;
                aw[0] = (_Float16)a.x; aw[1] = (_Float16)a.y;
                aw[2] = (_Float16)a.z; aw[3] = (_Float16)a.w;
                *(h4*)(awrite + (size_t)idx * 4) = aw;
            }
        }
    }
    const int h = lane >> 4;
    float4 acc = {0.f, 0.f, 0.f, 0.f};
    const int cap = r0 + 64;
    for (int i = r0; i < cap; i++) {
        int p = pk[i];
        float av = a_lds[wave][(i - r0) * 4 + h];
        h4 f = *(const h4*)(feat + (size_t)(p & 0xFFFF) * 256 + lane * 4);
        acc.x = fmaf(av, (float)f[0], acc.x);
        acc.y = fmaf(av, (float)f[1], acc.y);
        acc.z = fmaf(av, (float)f[2], acc.z);
        acc.w = fmaf(av, (float)f[3], acc.w);
    }
    {
        float mh = sel4(m4, h), invh = sel4(inv4, h), erh = sel4(er4, h);
        for (int i = cap; i < r1; i++) {
            int p = pk[i];
            int s = p & 0xFFFF, t = p >> 16;
            float v = el[s * 4 + h] + erh + es[t * 4 + h];
            v = v > 0.f ? v : SLOPE * v;
            float a = __expf(v - mh) * invh;
            if (HAS_PREV) a = a * (1.f - ALPHA) + ALPHA * (float)aprev[(size_t)i * 4 + h];
            h4 f = *(const h4*)(feat + (size_t)s * 256 + lane * 4);
            acc.x = fmaf(a, (float)f[0], acc.x);
            acc.y = fmaf(a, (float)f[1], acc.y);
            acc.z = fmaf(a, (float)f[2], acc.z);
            acc.w = fmaf(a, (float)f[3], acc.w);
        }
    }
    if (HAS_RES) {
        h4 rv = *(const h4*)(resh + (size_t)n * 256 + lane * 4);
        acc.x += (float)rv[0]; acc.y += (float)rv[1];
        acc.z += (float)rv[2]; acc.w += (float)rv[3];
    }
    acc.x = acc.x > 0.f ? acc.x : expm1f(acc.x);
    acc.y = acc.y > 0.f ? acc.y : expm1f(acc.y);
    acc.z = acc.z > 0.f ? acc.z : expm1f(acc.z);
    acc.w = acc.w > 0.f ? acc.w : expm1f(acc.w);
    h4 o;
    o[0] = (_Float16)acc.x; o[1] = (_Float16)acc.y;
    o[2] = (_Float16)acc.z; o[3] = (_Float16)acc.w;
    *(h4*)(outh + (size_t)n * 256 + lane * 4) = o;
}

// ---------------- fused GAT layer 2 (H=1, C=16): one wave per node ----------------

__global__ __launch_bounds__(256) void gat_fused1(const int* __restrict__ rowstart,
                                                  const int* __restrict__ pk,
                                                  const float* __restrict__ el,
                                                  const float* __restrict__ er,
                                                  const float* __restrict__ es,
                                                  const float* __restrict__ cpack,
                                                  float* __restrict__ out, int nN) {
    const int wave = threadIdx.x >> 6;
    const int lane = threadIdx.x & 63;
    int n = blockIdx.x * 4 + wave;
    if (n >= nN) return;
    const int r0 = rowstart[n], r1 = rowstart[n + 1];
    const int deg = r1 - r0;
    const float ern = er[n];

    if (deg <= 64) {
        const int idx = r0 + lane;
        const bool act = idx < r1;
        int p = act ? pk[idx] : 0;
        int psrc = p & 0xFFFF;
        float v = -INFINITY;
        if (act) {
            float t = el[psrc] + ern + es[p >> 16];
            v = t > 0.f ? t : SLOPE * t;
        }
        float m = v;
        #pragma unroll
        for (int off = 1; off < 64; off <<= 1) m = fmaxf(m, __shfl_xor(m, off));
        float ex = act ? __expf(v - m) : 0.f;
        float s = ex;
        #pragma unroll
        for (int off = 1; off < 64; off <<= 1) s += __shfl_xor(s, off);
        float a = ex / (s + 1e-9f);

        const int eslot = lane >> 4, fl = lane & 15;
        float acc = 0.f;
        int i = r0;
        for (; i + 7 < r1; i += 8) {
            int j0 = (i - r0) + eslot;
            int j1 = j0 + 4;
            int s0 = __shfl(psrc, j0);
            int s1 = __shfl(psrc, j1);
            float a0 = __shfl(a, j0);
            float a1 = __shfl(a, j1);
            float f0 = cpack[(size_t)s0 * 32 + fl];
            float f1 = cpack[(size_t)s1 * 32 + fl];
            acc = fmaf(a0, f0, acc);
            acc = fmaf(a1, f1, acc);
        }
        for (; i + 3 < r1; i += 4) {
            int j = (i - r0) + eslot;
            int sj = __shfl(psrc, j);
            float aj = __shfl(a, j);
            acc = fmaf(aj, cpack[(size_t)sj * 32 + fl], acc);
        }
        int rem = r1 - i;
        if (rem > 0) {   // wave-uniform branch: full exec for the shfls below
            int j = (i - r0) + (eslot < rem ? eslot : rem - 1);
            int sj = __shfl(psrc, j);
            float aj = __shfl(a, j);
            if (eslot >= rem) aj = 0.f;   // masked lanes contribute nothing
            acc = fmaf(aj, cpack[(size_t)sj * 32 + fl], acc);
        }
        acc += __shfl_xor(acc, 16);
        acc += __shfl_xor(acc, 32);
        if (lane < 16) out[(size_t)n * 16 + lane] = acc + cpack[(size_t)n * 32 + 16 + lane];
        return;
    }

    // fallback deg > 64 (rare)
    float m = -INFINITY;
    for (int base = r0; base < r1; base += 64) {
        int idx = base + lane;
        if (idx < r1) {
            int p = pk[idx];
            float v = el[p & 0xFFFF] + ern + es[p >> 16];
            v = v > 0.f ? v : SLOPE * v;
            m = fmaxf(m, v);
        }
    }
    #pragma unroll
    for (int off = 1; off < 64; off <<= 1) m = fmaxf(m, __shfl_xor(m, off));
    float s = 0.f;
    for (int base = r0; base < r1; base += 64) {
        int idx = base + lane;
        if (idx < r1) {
            int p = pk[idx];
            float v = el[p & 0xFFFF] + ern + es[p >> 16];
            v = v > 0.f ? v : SLOPE * v;
            s += __expf(v - m);
        }
    }
    #pragma unroll
    for (int off = 1; off < 64; off <<= 1) s += __shfl_xor(s, off);
    float inv = 1.f / (s + 1e-9f);
    const int eslot = lane >> 4, fl = lane & 15;
    float acc = 0.f;
    for (int i = r0; i < r1; i += 4) {
        int rem = r1 - i;
        if (eslot < rem) {   // no shfl inside: divergence safe
            int j = i + eslot;
            int p = pk[j];
            float v = el[p & 0xFFFF] + ern + es[p >> 16];
            v = v > 0.f ? v : SLOPE * v;
            float a = __expf(v - m) * inv;
            acc = fmaf(a, cpack[(size_t)(p & 0xFFFF) * 32 + fl], acc);
        }
    }
    acc += __shfl_xor(acc, 16);
    acc += __shfl_xor(acc, 32);
    if (lane < 16) out[(size_t)n * 16 + lane] = acc + cpack[(size_t)n * 32 + 16 + lane];
}

// ---------------- host ----------------

extern "C" void kernel_launch(void* const* d_in, const int* in_sizes, int n_in,
                              void* d_out, int out_size, void* d_ws, size_t ws_size,
                              hipStream_t stream) {
    const float* x0 = (const float*)d_in[0];
    const float* x1 = (const float*)d_in[1];
    const float* x2 = (const float*)d_in[2];
    const int* src  = (const int*)d_in[3];
    const int* dst  = (const int*)d_in[4];
    const int* et   = (const int*)d_in[5];
    const float* W0 = (const float*)d_in[6];  const float* b0 = (const float*)d_in[7];
    const float* W1 = (const float*)d_in[8];  const float* b1 = (const float*)d_in[9];
    const float* W2 = (const float*)d_in[10]; const float* b2 = (const float*)d_in[11];
    const float* Wg0 = (const float*)d_in[12]; const float* etab0 = (const float*)d_in[13];
    const float* We0 = (const float*)d_in[14]; const float* al0 = (const float*)d_in[15];
    const float* ar0 = (const float*)d_in[16]; const float* ae0 = (const float*)d_in[17];
    const float* Wg1 = (const float*)d_in[18]; const float* etab1 = (const float*)d_in[19];
    const float* We1 = (const float*)d_in[20]; const float* al1 = (const float*)d_in[21];
    const float* ar1 = (const float*)d_in[22]; const float* ae1 = (const float*)d_in[23];
    const float* Wg2 = (const float*)d_in[24]; const float* etab2 = (const float*)d_in[25];
    const float* We2 = (const float*)d_in[26]; const float* al2 = (const float*)d_in[27];
    const float* ar2 = (const float*)d_in[28]; const float* ae2 = (const float*)d_in[29];
    const float* resW2 = (const float*)d_in[30];
    float* outp = (float*)d_out;

    char* p = (char*)d_ws;
    auto alloc = [&](size_t bytes) -> void* {
        void* r = (void*)p;
        p += (bytes + 255) & ~(size_t)255;
        return r;
    };
    _Float16* x0h   = (_Float16*)alloc((size_t)N0 * 128 * 2);
    _Float16* x1h   = (_Float16*)alloc((size_t)N1 * 64 * 2);
    _Float16* x2h   = (_Float16*)alloc((size_t)N2 * 32 * 2);
    _Float16* W0h   = (_Float16*)alloc(64 * 128 * 2);
    _Float16* W1h   = (_Float16*)alloc(64 * 64 * 2);
    _Float16* W2h   = (_Float16*)alloc(64 * 32 * 2);
    _Float16* Wg0h  = (_Float16*)alloc(256 * 64 * 2);
    _Float16* Wg1h  = (_Float16*)alloc(256 * 256 * 2);
    _Float16* wpkh  = (_Float16*)alloc(32 * 256 * 2);
    _Float16* h0h   = (_Float16*)alloc((size_t)NN * 64 * 2);
    _Float16* feath = (_Float16*)alloc((size_t)NN * 256 * 2);
    _Float16* bufAh = (_Float16*)alloc((size_t)NN * 256 * 2);
    _Float16* bufBh = (_Float16*)alloc((size_t)NN * 256 * 2);
    _Float16* a0h   = (_Float16*)alloc((size_t)EE * 4 * 2);
    float* el    = (float*)alloc((size_t)NN * 4 * 4);
    float* er    = (float*)alloc((size_t)NN * 4 * 4);
    float* es    = (float*)alloc(96 * 4);
    float* cpack = (float*)alloc((size_t)NN * 32 * 4);
    int* rowstart = (int*)alloc((size_t)(NN + 1) * 4);
    int* deg      = (int*)alloc((size_t)NN * 4);
    int* cursor   = (int*)alloc((size_t)NN * 4);
    int* bsum     = (int*)alloc(256 * 4);
    int* pk       = (int*)alloc((size_t)EE * 4);

    const int EB = (EE + 255) / 256;        // 3125
    const int NB = (NN + 255) / 256;        // 196
    const int NHB = (NN * 4 + 255) / 256;   // 782
    const int MB128 = (NN + 127) / 128;     // 391
    const int WB = (NN + 3) / 4;            // 12500

    // CSR build
    hipMemsetAsync(deg, 0, (size_t)NN * 4, stream);
    hist_kernel<<<EB, 256, 0, stream>>>(dst, deg, EE);
    block_sum_kernel<<<NB, 256, 0, stream>>>(deg, bsum, NN);
    scan_bsum_kernel<<<1, 256, 0, stream>>>(bsum, NB);
    scan_out_kernel<<<NB, 256, 0, stream>>>(deg, bsum, rowstart, cursor, NN);
    scatter_kernel<<<EB, 256, 0, stream>>>(src, dst, et, cursor, pk, EE);

    // es tables + weight/feature converts
    es_table_all<<<72, 64, 0, stream>>>(etab0, We0, ae0, etab1, We1, ae1, etab2, We2, ae2, es);
    {
        int n0c = N0 * 128, n1c = N1 * 64, n2c = N2 * 32;
        int total = n0c + n1c + n2c + 8192 + 4096 + 2048 + 16384 + 65536 + 4096 + 4096;
        f2h10<<<(total + 255) / 256, 256, 0, stream>>>(
            x0, x0h, n0c, x1, x1h, n1c, x2, x2h, n2c,
            W0, W0h, 8192, W1, W1h, 4096, W2, W2h, 2048,
            Wg0, Wg0h, 16384, Wg1, Wg1h, 65536,
            Wg2, wpkh, 4096, resW2, wpkh + 4096, 4096);
    }

    // input projections -> h0h [N,64] fp16
    gemm_mfma<4><<<dim3((N0 + 127) / 128, 1), 256, 0, stream>>>(x0h, W0h, b0, nullptr, h0h, N0, 64, 128);
    gemm_mfma<4><<<dim3((N1 + 127) / 128, 1), 256, 0, stream>>>(x1h, W1h, b1, nullptr, h0h + (size_t)N0 * 64, N1, 64, 64);
    gemm_mfma<4><<<dim3((N2 + 127) / 128, 1), 256, 0, stream>>>(x2h, W2h, b2, nullptr, h0h + (size_t)(N0 + N1) * 64, N2, 64, 32);

    // ---- GAT layer 0 ----
    gemm_mfma<8><<<dim3(MB128, 2), 256, 0, stream>>>(h0h, Wg0h, nullptr, nullptr, feath, NN, 256, 64);
    node_elr_h<<<NHB, 256, 0, stream>>>(feath, al0, ar0, el, er, NN);
    gat_fused4<true, false, false><<<WB, 256, 0, stream>>>(
        rowstart, pk, el, er, es + 0, feath, nullptr, a0h, nullptr, bufAh, NN);

    // ---- GAT layer 1 ----
    gemm_mfma<8><<<dim3(MB128, 2), 256, 0, stream>>>(bufAh, Wg1h, nullptr, nullptr, feath, NN, 256, 256);
    node_elr_h<<<NHB, 256, 0, stream>>>(feath, al1, ar1, el, er, NN);
    gat_fused4<false, true, true><<<WB, 256, 0, stream>>>(
        rowstart, pk, el, er, es + 32, feath, a0h, nullptr, bufAh, bufBh, NN);

    // ---- GAT layer 2 (H=1, C=16, linear residual, no act) ----
    gemm_mfma<2><<<dim3(MB128, 1), 256, 0, stream>>>(bufBh, wpkh, nullptr, cpack, nullptr, NN, 32, 256);
    node_elr_f2<<<NB, 256, 0, stream>>>(cpack, al2, ar2, el, er, NN);
    gat_fused1<<<WB, 256, 0, stream>>>(rowstart, pk, el, er, es + 64, cpack, outp, NN);
}